// Round 3
// baseline (147.881 us; speedup 1.0000x reference)
//
#include <hip/hip_runtime.h>

#define NB   8192
#define HD   1024
#define HFD  1152
#define NK0  64
#define NK1  256
#define DD   128

typedef __attribute__((ext_vector_type(4))) float  f32x4;
typedef __attribute__((ext_vector_type(8))) __bf16 bf16x8;

__device__ __forceinline__ unsigned short f2bf(float f) {
  unsigned int u = __float_as_uint(f);
  u += 0x7fffu + ((u >> 16) & 1u);
  return (unsigned short)(u >> 16);
}
__device__ __forceinline__ unsigned int pack2(float a, float b) {
  return (unsigned int)f2bf(a) | ((unsigned int)f2bf(b) << 16);
}
__device__ __forceinline__ uint4 pack8(const float4 a, const float4 b) {
  return make_uint4(pack2(a.x, a.y), pack2(a.z, a.w), pack2(b.x, b.y), pack2(b.z, b.w));
}

// ---- K0: f32 -> bf16 conversions + codebook norms -------------------------
// blocks: [0,4096) x | [4096,4160) Wc | [4160,4232) Wf | [4232,5256) fcb
//         [5256,5260) ccb | [5260,5324) fine norms | [5324] coarse norms
__global__ __launch_bounds__(256) void k0_convert(
    const float* __restrict__ x, const float* __restrict__ Wc,
    const float* __restrict__ Wf, const float* __restrict__ fcb,
    const float* __restrict__ ccb,
    unsigned short* __restrict__ xbf, unsigned short* __restrict__ Wcbf,
    unsigned short* __restrict__ Wfbf, unsigned short* __restrict__ fcbbf,
    unsigned short* __restrict__ ccbbf,
    float* __restrict__ cn_all, float* __restrict__ cn_c)
{
  const int bid = blockIdx.x, t = threadIdx.x;
  const float* src; unsigned short* dst; long e0;
  if (bid < 4096)      { src = x;   dst = xbf;   e0 = ((long)bid * 256 + t) * 8; }
  else if (bid < 4160) { src = Wc;  dst = Wcbf;  e0 = ((long)(bid - 4096) * 256 + t) * 8; }
  else if (bid < 4232) { src = Wf;  dst = Wfbf;  e0 = ((long)(bid - 4160) * 256 + t) * 8; }
  else if (bid < 5256) { src = fcb; dst = fcbbf; e0 = ((long)(bid - 4232) * 256 + t) * 8; }
  else if (bid < 5260) { src = ccb; dst = ccbbf; e0 = ((long)(bid - 5256) * 256 + t) * 8; }
  else if (bid < 5324) {
    const int row = (bid - 5260) * 256 + t;
    const float* r = fcb + (size_t)row * DD;
    float s = 0.f;
#pragma unroll
    for (int i = 0; i < 32; ++i) {
      const float4 v = *(const float4*)&r[i * 4];
      s += v.x * v.x + v.y * v.y + v.z * v.z + v.w * v.w;
    }
    cn_all[row] = s;
    return;
  } else {
    if (t < 64) {
      const float* r = ccb + (size_t)t * DD;
      float s = 0.f;
#pragma unroll
      for (int i = 0; i < 32; ++i) {
        const float4 v = *(const float4*)&r[i * 4];
        s += v.x * v.x + v.y * v.y + v.z * v.z + v.w * v.w;
      }
      cn_c[t] = s;
    }
    return;
  }
  const float4 a = *(const float4*)&src[e0];
  const float4 b = *(const float4*)&src[e0 + 4];
  *(uint4*)&dst[e0] = pack8(a, b);
}

// ---- K12: vid<512 = GEMM1+LN+coarseVQ (BM=16); vid>=512 = GEMM2a ----------
// BM=16, BN=128, BK=64, 4 waves, 2-deep register prefetch, grid 1024.
__global__ __launch_bounds__(256) void k12_gemm(
    const unsigned short* __restrict__ xbf, const unsigned short* __restrict__ Wcbf,
    const unsigned short* __restrict__ Wfbf, const unsigned short* __restrict__ ccbbf,
    const float* __restrict__ ccb, const float* __restrict__ bc,
    const float* __restrict__ gc, const float* __restrict__ betac,
    const float* __restrict__ cn_c,
    float* __restrict__ out0, unsigned short* __restrict__ zcq_bf,
    int* __restrict__ ci_g, int* __restrict__ counts,
    float* __restrict__ coarse_partial, float* __restrict__ p2a)
{
  extern __shared__ char smem[];
  unsigned short* As = (unsigned short*)smem;             // [16][72] bf16
  unsigned short* Bs = (unsigned short*)(smem + 2304);    // [128][72] bf16
  float*          zcf = (float*)smem;                     // [16][132] f32 overlay
  unsigned short* cbb = (unsigned short*)(smem + 8448);   // [64][136] bf16
  unsigned short* zbb = (unsigned short*)(smem + 25856);  // [16][136] bf16
  float* zn  = (float*)(smem + 30208);                    // [16]
  float* cnS = (float*)(smem + 30272);                    // [64]
  float* dmS = (float*)(smem + 30528);                    // [4][16]
  int*   imS = (int*)  (smem + 30784);                    // [4][16]
  int*   cxS = (int*)  (smem + 31040);                    // [16]

  const int t = threadIdx.x, lane = t & 63, wid = t >> 6;
  const int l15 = lane & 15, lhi = lane >> 4;
  const int vid = (blockIdx.x & 7) * 128 + (blockIdx.x >> 3);  // XCD-chunked
  const int role = vid >> 9;
  const int mi = vid & 511;
  const int m0 = mi * 16;
  const unsigned short* Wb = role ? Wfbf : Wcbf;
  const int ldb = role ? HFD : HD;
  const int arow = t >> 4, ac4 = (t & 15) * 4;   // A staging: uint2 per thread
  const int br = t >> 3, bc8 = (t & 7) * 8;      // B staging: 4x uint4

  f32x4 acc[2];
  acc[0] = (f32x4){0.f, 0.f, 0.f, 0.f};
  acc[1] = (f32x4){0.f, 0.f, 0.f, 0.f};

  uint2 ra[2]; uint4 rb[2][4];
#define LOADT(kt, s)                                                           \
  {                                                                            \
    ra[s] = *(const uint2*)&xbf[(size_t)(m0 + arow) * HD + (kt) * 64 + ac4];   \
    const unsigned short* bp = &Wb[(size_t)br * ldb + (kt) * 64 + bc8];        \
    rb[s][0] = *(const uint4*)bp;              rb[s][1] = *(const uint4*)(bp + 32 * ldb); \
    rb[s][2] = *(const uint4*)(bp + 64 * ldb); rb[s][3] = *(const uint4*)(bp + 96 * ldb); \
  }

  LOADT(0, 0); LOADT(1, 1);
  for (int kt = 0; kt < 16; ++kt) {
    const int s = kt & 1;
    __syncthreads();
    *(uint2*)&As[arow * 72 + ac4] = ra[s];
#pragma unroll
    for (int i = 0; i < 4; ++i) *(uint4*)&Bs[(br + i * 32) * 72 + bc8] = rb[s][i];
    if (kt < 14) LOADT(kt + 2, s);
    __syncthreads();
#pragma unroll
    for (int ks = 0; ks < 2; ++ks) {
      const int lk = ks * 32 + lhi * 8;
      bf16x8 a  = *(const bf16x8*)&As[l15 * 72 + lk];
      bf16x8 b0 = *(const bf16x8*)&Bs[(wid * 32 + l15) * 72 + lk];
      bf16x8 b1 = *(const bf16x8*)&Bs[(wid * 32 + 16 + l15) * 72 + lk];
      acc[0] = __builtin_amdgcn_mfma_f32_16x16x32_bf16(a, b0, acc[0], 0, 0, 0);
      acc[1] = __builtin_amdgcn_mfma_f32_16x16x32_bf16(a, b1, acc[1], 0, 0, 0);
    }
  }
#undef LOADT

  if (role) {  // GEMM2a partial (f32)
#pragma unroll
    for (int n = 0; n < 2; ++n)
#pragma unroll
      for (int r = 0; r < 4; ++r)
        p2a[(size_t)(m0 + lhi * 4 + r) * DD + wid * 32 + n * 16 + l15] = acc[n][r];
    return;
  }

  // ---- coarse epilogue ----
  __syncthreads();   // all MFMA LDS reads done; staging region dead
#pragma unroll
  for (int n = 0; n < 2; ++n)
#pragma unroll
    for (int r = 0; r < 4; ++r) {
      int col = wid * 32 + n * 16 + l15;
      zcf[(lhi * 4 + r) * 132 + col] = acc[n][r] + bc[col];
    }
#pragma unroll
  for (int i = 0; i < 4; ++i) {   // stage coarse codebook bf16
    int idx = t + i * 256; int row = idx >> 4, c8 = (idx & 15) * 8;
    *(uint4*)&cbb[row * 136 + c8] = *(const uint4*)&ccbbf[row * DD + c8];
  }
  if (t < 64) cnS[t] = cn_c[t];
  __syncthreads();
  {  // LayerNorm: 16 threads/row, 8 cols each; capture ||z||^2
    const int r = t >> 4, p = t & 15;
    float v[8];
    const float4 u0 = *(const float4*)&zcf[r * 132 + p * 8];
    const float4 u1 = *(const float4*)&zcf[r * 132 + p * 8 + 4];
    v[0]=u0.x; v[1]=u0.y; v[2]=u0.z; v[3]=u0.w; v[4]=u1.x; v[5]=u1.y; v[6]=u1.z; v[7]=u1.w;
    float s = 0.f, s2 = 0.f;
#pragma unroll
    for (int j = 0; j < 8; ++j) { s += v[j]; s2 += v[j] * v[j]; }
#pragma unroll
    for (int off = 1; off < 16; off <<= 1) { s += __shfl_xor(s, off); s2 += __shfl_xor(s2, off); }
    const float mu   = s * (1.f / 128.f);
    const float rstd = rsqrtf(s2 * (1.f / 128.f) - mu * mu + 1e-5f);
    float s2n = 0.f;
#pragma unroll
    for (int j = 0; j < 8; ++j) {
      int col = p * 8 + j;
      float vv = (v[j] - mu) * rstd * gc[col] + betac[col];
      v[j] = vv; s2n += vv * vv;
    }
#pragma unroll
    for (int off = 1; off < 16; off <<= 1) s2n += __shfl_xor(s2n, off);
    if (p == 0) zn[r] = s2n;
    *(uint4*)&zbb[r * 136 + p * 8] =
        make_uint4(pack2(v[0], v[1]), pack2(v[2], v[3]), pack2(v[4], v[5]), pack2(v[6], v[7]));
  }
  __syncthreads();
  {  // coarse distances via MFMA: D[code][zrow]
    f32x4 dacc = (f32x4){0.f, 0.f, 0.f, 0.f};
#pragma unroll
    for (int ks = 0; ks < 4; ++ks) {
      const int lk = ks * 32 + lhi * 8;
      bf16x8 a = *(const bf16x8*)&cbb[(wid * 16 + l15) * 136 + lk];
      bf16x8 b = *(const bf16x8*)&zbb[l15 * 136 + lk];
      dacc = __builtin_amdgcn_mfma_f32_16x16x32_bf16(a, b, dacc, 0, 0, 0);
    }
    float bd = 3.4e38f; int bi = 0;
#pragma unroll
    for (int r = 0; r < 4; ++r) {
      int code = wid * 16 + lhi * 4 + r;
      float d = cnS[code] - 2.f * dacc[r];
      if (d < bd) { bd = d; bi = code; }
    }
#pragma unroll
    for (int off = 16; off < 64; off <<= 1) {
      float od = __shfl_xor(bd, off); int oi = __shfl_xor(bi, off);
      if (od < bd || (od == bd && oi < bi)) { bd = od; bi = oi; }
    }
    if (lhi == 0) { dmS[wid * 16 + l15] = bd; imS[wid * 16 + l15] = bi; }
  }
  __syncthreads();
  if (t < 16) {
    float bd = dmS[t]; int bi = imS[t];
#pragma unroll
    for (int w = 1; w < 4; ++w) {
      float od = dmS[w * 16 + t]; int oi = imS[w * 16 + t];
      if (od < bd || (od == bd && oi < bi)) { bd = od; bi = oi; }
    }
    ci_g[m0 + t] = bi;
    atomicAdd(&counts[bi], 1);
    cxS[t] = bi;
    float lp = bd + zn[t];
#pragma unroll
    for (int off = 1; off < 16; off <<= 1) lp += __shfl_xor(lp, off);
    if (t == 0) coarse_partial[mi] = lp;
  }
  __syncthreads();
  {  // outputs: q gather (f32 + bf16)
    const int r = t >> 4, p = t & 15;
    const int c = cxS[r];
    const float4 q0 = *(const float4*)&ccb[c * DD + p * 8];
    const float4 q1 = *(const float4*)&ccb[c * DD + p * 8 + 4];
    *(float4*)&out0[(size_t)(m0 + r) * DD + p * 8]     = q0;
    *(float4*)&out0[(size_t)(m0 + r) * DD + p * 8 + 4] = q1;
    *(uint4*)&zcq_bf[(size_t)(m0 + r) * DD + p * 8] = *(const uint4*)&ccbbf[c * DD + p * 8];
  }
}

// ---- K2b: zf = LN(p2a + zcq @ Wfz^T + bias); store bf16 + ||zf||^2 --------
__global__ __launch_bounds__(256) void k2b(
    const unsigned short* __restrict__ zcq_bf, const unsigned short* __restrict__ Wfbf,
    const float* __restrict__ p2a, const float* __restrict__ bfv,
    const float* __restrict__ gf, const float* __restrict__ betaf,
    unsigned short* __restrict__ zf_bf, float* __restrict__ zfn)
{
  extern __shared__ char smem[];
  unsigned short* Zq = (unsigned short*)smem;             // [32][136]
  unsigned short* Wz = (unsigned short*)(smem + 8704);    // [128][136]
  float* zff = (float*)smem;                              // [32][132] overlay

  const int t = threadIdx.x, lane = t & 63, wid = t >> 6;
  const int l15 = lane & 15, lhi = lane >> 4;
  const int m0 = blockIdx.x * 32;

#pragma unroll
  for (int i = 0; i < 2; ++i) {
    int idx = t + i * 256; int row = idx >> 4, c8 = (idx & 15) * 8;
    *(uint4*)&Zq[row * 136 + c8] = *(const uint4*)&zcq_bf[(size_t)(m0 + row) * DD + c8];
  }
#pragma unroll
  for (int i = 0; i < 8; ++i) {
    int idx = t + i * 256; int row = idx >> 4, c8 = (idx & 15) * 8;
    *(uint4*)&Wz[row * 136 + c8] = *(const uint4*)&Wfbf[(size_t)row * HFD + 1024 + c8];
  }
  __syncthreads();
  f32x4 acc[2][2];
#pragma unroll
  for (int m = 0; m < 2; ++m)
#pragma unroll
    for (int n = 0; n < 2; ++n) acc[m][n] = (f32x4){0.f, 0.f, 0.f, 0.f};
#pragma unroll
  for (int ks = 0; ks < 4; ++ks) {
    const int lk = ks * 32 + lhi * 8;
    bf16x8 a0 = *(const bf16x8*)&Zq[l15 * 136 + lk];
    bf16x8 a1 = *(const bf16x8*)&Zq[(16 + l15) * 136 + lk];
#pragma unroll
    for (int n = 0; n < 2; ++n) {
      bf16x8 b = *(const bf16x8*)&Wz[(wid * 32 + n * 16 + l15) * 136 + lk];
      acc[0][n] = __builtin_amdgcn_mfma_f32_16x16x32_bf16(a0, b, acc[0][n], 0, 0, 0);
      acc[1][n] = __builtin_amdgcn_mfma_f32_16x16x32_bf16(a1, b, acc[1][n], 0, 0, 0);
    }
  }
  __syncthreads();
#pragma unroll
  for (int m = 0; m < 2; ++m)
#pragma unroll
    for (int n = 0; n < 2; ++n)
#pragma unroll
      for (int r = 0; r < 4; ++r) {
        int row = m * 16 + lhi * 4 + r;
        int col = wid * 32 + n * 16 + l15;
        zff[row * 132 + col] = acc[m][n][r] + p2a[(size_t)(m0 + row) * DD + col] + bfv[col];
      }
  __syncthreads();
  {  // LN: 8 threads/row, 16 cols each
    const int r = t >> 3, p = t & 7;
    float v[16];
#pragma unroll
    for (int q = 0; q < 4; ++q) {
      const float4 u = *(const float4*)&zff[r * 132 + p * 16 + q * 4];
      v[q * 4] = u.x; v[q * 4 + 1] = u.y; v[q * 4 + 2] = u.z; v[q * 4 + 3] = u.w;
    }
    float s = 0.f, s2 = 0.f;
#pragma unroll
    for (int j = 0; j < 16; ++j) { s += v[j]; s2 += v[j] * v[j]; }
#pragma unroll
    for (int off = 1; off < 8; off <<= 1) { s += __shfl_xor(s, off); s2 += __shfl_xor(s2, off); }
    const float mu   = s * (1.f / 128.f);
    const float rstd = rsqrtf(s2 * (1.f / 128.f) - mu * mu + 1e-5f);
    float s2n = 0.f;
    unsigned int o[8];
#pragma unroll
    for (int jj = 0; jj < 8; ++jj) {
      int col = p * 16 + 2 * jj;
      float v0 = (v[2 * jj]     - mu) * rstd * gf[col]     + betaf[col];
      float v1 = (v[2 * jj + 1] - mu) * rstd * gf[col + 1] + betaf[col + 1];
      s2n += v0 * v0 + v1 * v1;
      o[jj] = pack2(v0, v1);
    }
#pragma unroll
    for (int off = 1; off < 8; off <<= 1) s2n += __shfl_xor(s2n, off);
    if (p == 0) zfn[m0 + r] = s2n;
    *(uint4*)&zf_bf[(size_t)(m0 + r) * DD + p * 16]     = make_uint4(o[0], o[1], o[2], o[3]);
    *(uint4*)&zf_bf[(size_t)(m0 + r) * DD + p * 16 + 8] = make_uint4(o[4], o[5], o[6], o[7]);
  }
}

// ---- bucketing ------------------------------------------------------------
__global__ void k_prefix(const int* __restrict__ counts, int* __restrict__ offsets,
                         int* __restrict__ cursor) {
  if (threadIdx.x == 0) {
    int run = 0;
    for (int g = 0; g < NK0; ++g) { offsets[g] = run; cursor[g] = run; run += counts[g]; }
  }
}
__global__ void k_scatter(const int* __restrict__ ci_g, int* __restrict__ cursor,
                          int* __restrict__ bucket_rows) {
  int i = blockIdx.x * 256 + threadIdx.x;
  int pos = atomicAdd(&cursor[ci_g[i]], 1);
  bucket_rows[pos] = i;
}

// ---- K3: per-(chunk,group) fine VQ ----------------------------------------
__global__ __launch_bounds__(256) void k3_fine(
    const unsigned short* __restrict__ zf_bf, const unsigned short* __restrict__ fcbbf,
    const float* __restrict__ fcb, const float* __restrict__ cn_all,
    const float* __restrict__ zfn,
    const int* __restrict__ counts, const int* __restrict__ offsets,
    const int* __restrict__ bucket_rows,
    float* __restrict__ out1, float* __restrict__ fine_partial)
{
  extern __shared__ char smem[];
  unsigned short* Vb  = (unsigned short*)smem;            // [256][136]
  unsigned short* zfL = (unsigned short*)(smem + 69632);  // [32][136]
  int*   ridS = (int*)  (smem + 78336);                   // [32]
  float* dmS  = (float*)(smem + 78464);                   // [4][32]
  int*   imS  = (int*)  (smem + 78976);                   // [4][32]
  int*   fiS  = (int*)  (smem + 79488);                   // [32]

  const int g = blockIdx.y, cx = blockIdx.x;   // cx in [0,4)
  const int t = threadIdx.x, lane = t & 63, wid = t >> 6;
  const int l15 = lane & 15, lhi = lane >> 4;
  const int count = counts[g], start = offsets[g];

  float lp = 0.f;
  if (cx * 32 < count) {
#pragma unroll
    for (int i = 0; i < 16; ++i) {   // full 256x128 bf16 codebook
      int idx = t + i * 256; int row = idx >> 4, c8 = (idx & 15) * 8;
      *(uint4*)&Vb[row * 136 + c8] = *(const uint4*)&fcbbf[((size_t)g * NK1 + row) * DD + c8];
    }
    float cnr[4];
#pragma unroll
    for (int n = 0; n < 4; ++n) cnr[n] = cn_all[g * NK1 + wid * 64 + n * 16 + l15];

    for (int r0 = cx * 32; r0 < count; r0 += 128) {
      __syncthreads();
      if (t < 32) ridS[t] = (r0 + t < count) ? bucket_rows[start + r0 + t] : -1;
      __syncthreads();
#pragma unroll
      for (int i = 0; i < 2; ++i) {
        int idx = t + i * 256; int row = idx >> 4, c8 = (idx & 15) * 8;
        int rid = ridS[row];
        uint4 v = make_uint4(0u, 0u, 0u, 0u);
        if (rid >= 0) v = *(const uint4*)&zf_bf[(size_t)rid * DD + c8];
        *(uint4*)&zfL[row * 136 + c8] = v;
      }
      __syncthreads();
      f32x4 acc[2][4];
#pragma unroll
      for (int m = 0; m < 2; ++m)
#pragma unroll
        for (int n = 0; n < 4; ++n) acc[m][n] = (f32x4){0.f, 0.f, 0.f, 0.f};
#pragma unroll
      for (int ks = 0; ks < 4; ++ks) {
        const int lk = ks * 32 + lhi * 8;
        bf16x8 a0 = *(const bf16x8*)&zfL[l15 * 136 + lk];
        bf16x8 a1 = *(const bf16x8*)&zfL[(16 + l15) * 136 + lk];
#pragma unroll
        for (int n = 0; n < 4; ++n) {
          bf16x8 b = *(const bf16x8*)&Vb[(wid * 64 + n * 16 + l15) * 136 + lk];
          acc[0][n] = __builtin_amdgcn_mfma_f32_16x16x32_bf16(a0, b, acc[0][n], 0, 0, 0);
          acc[1][n] = __builtin_amdgcn_mfma_f32_16x16x32_bf16(a1, b, acc[1][n], 0, 0, 0);
        }
      }
#pragma unroll
      for (int m = 0; m < 2; ++m)
#pragma unroll
        for (int r = 0; r < 4; ++r) {
          float bd = 3.4e38f; int bi = 0;
#pragma unroll
          for (int n = 0; n < 4; ++n) {
            int code = wid * 64 + n * 16 + l15;
            float d = cnr[n] - 2.f * acc[m][n][r];
            if (d < bd || (d == bd && code < bi)) { bd = d; bi = code; }
          }
#pragma unroll
          for (int off = 1; off < 16; off <<= 1) {
            float od = __shfl_xor(bd, off); int oi = __shfl_xor(bi, off);
            if (od < bd || (od == bd && oi < bi)) { bd = od; bi = oi; }
          }
          if (l15 == 0) {
            int row = m * 16 + lhi * 4 + r;
            dmS[wid * 32 + row] = bd; imS[wid * 32 + row] = bi;
          }
        }
      __syncthreads();
      if (t < 32) {
        float bd = dmS[t]; int bi = imS[t];
#pragma unroll
        for (int w = 1; w < 4; ++w) {
          float od = dmS[w * 32 + t]; int oi = imS[w * 32 + t];
          if (od < bd || (od == bd && oi < bi)) { bd = od; bi = oi; }
        }
        fiS[t] = bi;
        int rid = ridS[t];
        if (rid >= 0) lp += bd + zfn[rid];
      }
      __syncthreads();
      {  // zfq output (float4-vectorized)
        const int r = t >> 3, p = t & 7;
        const int rid = ridS[r];
        if (rid >= 0) {
          const int fi = fiS[r];
          const float* qr = &fcb[((size_t)g * NK1 + fi) * DD + p * 16];
          float* orow = &out1[(size_t)rid * DD + p * 16];
#pragma unroll
          for (int q = 0; q < 4; ++q) *(float4*)&orow[q * 4] = *(const float4*)&qr[q * 4];
        }
      }
    }
  }
#pragma unroll
  for (int off = 1; off < 32; off <<= 1) lp += __shfl_xor(lp, off);
  if (t == 0) fine_partial[g * 4 + cx] = lp;
}

// ---- K4: loss reduce (one wave) -------------------------------------------
__global__ void k_final(const float* __restrict__ coarse_partial,
                        const float* __restrict__ fine_partial,
                        float* __restrict__ outL) {
  const int t = threadIdx.x;
  float s = 0.f;
#pragma unroll
  for (int i = 0; i < 8; ++i) s += coarse_partial[t + i * 64];
#pragma unroll
  for (int i = 0; i < 4; ++i) s += fine_partial[t + i * 64];
#pragma unroll
  for (int off = 1; off < 64; off <<= 1) s += __shfl_xor(s, off);
  if (t == 0) outL[0] = 1.25f * s / 1048576.0f;
}

// ---- launcher -------------------------------------------------------------
extern "C" void kernel_launch(void* const* d_in, const int* in_sizes, int n_in,
                              void* d_out, int out_size, void* d_ws, size_t ws_size,
                              hipStream_t stream) {
  const float* x     = (const float*)d_in[0];
  const float* Wc    = (const float*)d_in[1];
  const float* bc    = (const float*)d_in[2];
  const float* gc    = (const float*)d_in[3];
  const float* betac = (const float*)d_in[4];
  const float* ccb   = (const float*)d_in[5];
  const float* Wf    = (const float*)d_in[6];
  const float* bfv   = (const float*)d_in[7];
  const float* gf    = (const float*)d_in[8];
  const float* betaf = (const float*)d_in[9];
  const float* fcb   = (const float*)d_in[10];

  float* out0 = (float*)d_out;
  float* out1 = out0 + (size_t)NB * DD;
  float* outL = out0 + (size_t)2 * NB * DD;

  char* ws = (char*)d_ws;
  unsigned short* xbf    = (unsigned short*)(ws);
  unsigned short* Wcbf   = (unsigned short*)(ws + 16777216);
  unsigned short* Wfbf   = (unsigned short*)(ws + 17039360);
  unsigned short* fcbbf  = (unsigned short*)(ws + 17334272);
  unsigned short* ccbbf  = (unsigned short*)(ws + 21528576);
  float*          cn_all = (float*)(ws + 21544960);
  float*          cn_c   = (float*)(ws + 21610496);
  float*          p2a    = (float*)(ws + 21610752);
  unsigned short* zcq_bf = (unsigned short*)(ws + 25805056);
  unsigned short* zf_bf  = (unsigned short*)(ws + 27902208);
  float*          zfn    = (float*)(ws + 29999360);
  int* ci_g        = (int*)(ws + 30032128);
  int* bucket_rows = (int*)(ws + 30064896);
  int* counts      = (int*)(ws + 30097664);
  int* offsets     = (int*)(ws + 30097920);
  int* cursor      = (int*)(ws + 30098176);
  float* coarse_partial = (float*)(ws + 30098432);
  float* fine_partial   = (float*)(ws + 30100480);

  hipFuncSetAttribute(reinterpret_cast<const void*>(k12_gemm),
                      hipFuncAttributeMaxDynamicSharedMemorySize, 31104);
  hipFuncSetAttribute(reinterpret_cast<const void*>(k2b),
                      hipFuncAttributeMaxDynamicSharedMemorySize, 43520);
  hipFuncSetAttribute(reinterpret_cast<const void*>(k3_fine),
                      hipFuncAttributeMaxDynamicSharedMemorySize, 79616);

  hipMemsetAsync(ws + 30097664, 0, 3840, stream);

  hipLaunchKernelGGL(k0_convert, dim3(5325), dim3(256), 0, stream,
                     x, Wc, Wf, fcb, ccb, xbf, Wcbf, Wfbf, fcbbf, ccbbf, cn_all, cn_c);
  hipLaunchKernelGGL(k12_gemm, dim3(1024), dim3(256), 31104, stream,
                     xbf, Wcbf, Wfbf, ccbbf, ccb, bc, gc, betac, cn_c,
                     out0, zcq_bf, ci_g, counts, coarse_partial, p2a);
  hipLaunchKernelGGL(k2b, dim3(256), dim3(256), 43520, stream,
                     zcq_bf, Wfbf, p2a, bfv, gf, betaf, zf_bf, zfn);
  hipLaunchKernelGGL(k_prefix, dim3(1), dim3(64), 0, stream, counts, offsets, cursor);
  hipLaunchKernelGGL(k_scatter, dim3(NB / 256), dim3(256), 0, stream, ci_g, cursor, bucket_rows);
  hipLaunchKernelGGL(k3_fine, dim3(4, 64), dim3(256), 79616, stream,
                     zf_bf, fcbbf, fcb, cn_all, zfn, counts, offsets, bucket_rows,
                     out1, fine_partial);
  hipLaunchKernelGGL(k_final, dim3(1), dim3(64), 0, stream, coarse_partial, fine_partial, outL);
}

// Round 4
// 98.449 us; speedup vs baseline: 1.5021x; 1.5021x over previous
//
#include <hip/hip_runtime.h>

#define NB   8192
#define HD   1024
#define HFD  1152
#define NK0  64
#define NK1  256
#define DD   128

typedef __attribute__((ext_vector_type(4))) float  f32x4;
typedef __attribute__((ext_vector_type(8))) __bf16 bf16x8;

__device__ __forceinline__ unsigned short f2bf(float f) {
  unsigned int u = __float_as_uint(f);
  u += 0x7fffu + ((u >> 16) & 1u);
  return (unsigned short)(u >> 16);
}
__device__ __forceinline__ unsigned int pack2(float a, float b) {
  return (unsigned int)f2bf(a) | ((unsigned int)f2bf(b) << 16);
}
__device__ __forceinline__ uint4 pack8(const float4 a, const float4 b) {
  return make_uint4(pack2(a.x, a.y), pack2(a.z, a.w), pack2(b.x, b.y), pack2(b.z, b.w));
}
__device__ __forceinline__ void gload_lds16(const void* g, void* l) {
  __builtin_amdgcn_global_load_lds(
      (const __attribute__((address_space(1))) void*)g,
      (__attribute__((address_space(3))) void*)l, 16, 0, 0);
}

// ---- K0: f32 -> bf16 conversions + codebook norms -------------------------
// blocks: [0,4096) x | [4096,4160) Wc->Wcomb[0:128] | [4160,4232) Wf->Wcomb[128:256]+Wfz
//         [4232,5256) fcb | [5256,5260) ccb | [5260,5324) fine norms | [5324] coarse norms
__global__ __launch_bounds__(256) void k0_convert(
    const float* __restrict__ x, const float* __restrict__ Wc,
    const float* __restrict__ Wf, const float* __restrict__ fcb,
    const float* __restrict__ ccb,
    unsigned short* __restrict__ xbf, unsigned short* __restrict__ Wcomb,
    unsigned short* __restrict__ Wfz, unsigned short* __restrict__ fcbbf,
    unsigned short* __restrict__ ccbbf,
    float* __restrict__ cn_all, float* __restrict__ cn_c)
{
  const int bid = blockIdx.x, t = threadIdx.x;
  if (bid < 4096) {
    long e0 = ((long)bid * 256 + t) * 8;
    const float4 a = *(const float4*)&x[e0];
    const float4 b = *(const float4*)&x[e0 + 4];
    *(uint4*)&xbf[e0] = pack8(a, b);
  } else if (bid < 4160) {
    long e0 = ((long)(bid - 4096) * 256 + t) * 8;
    const float4 a = *(const float4*)&Wc[e0];
    const float4 b = *(const float4*)&Wc[e0 + 4];
    *(uint4*)&Wcomb[e0] = pack8(a, b);
  } else if (bid < 4232) {
    long e0 = ((long)(bid - 4160) * 256 + t) * 8;
    const float4 a = *(const float4*)&Wf[e0];
    const float4 b = *(const float4*)&Wf[e0 + 4];
    const uint4 pk = pack8(a, b);
    const int row = (int)(e0 / HFD), c = (int)(e0 % HFD);
    if (c < 1024) *(uint4*)&Wcomb[(size_t)(128 + row) * HD + c] = pk;
    else          *(uint4*)&Wfz[(size_t)row * DD + (c - 1024)] = pk;
  } else if (bid < 5256) {
    long e0 = ((long)(bid - 4232) * 256 + t) * 8;
    const float4 a = *(const float4*)&fcb[e0];
    const float4 b = *(const float4*)&fcb[e0 + 4];
    *(uint4*)&fcbbf[e0] = pack8(a, b);
  } else if (bid < 5260) {
    long e0 = ((long)(bid - 5256) * 256 + t) * 8;
    const float4 a = *(const float4*)&ccb[e0];
    const float4 b = *(const float4*)&ccb[e0 + 4];
    *(uint4*)&ccbbf[e0] = pack8(a, b);
  } else if (bid < 5324) {
    const int row = (bid - 5260) * 256 + t;
    const float* r = fcb + (size_t)row * DD;
    float s = 0.f;
#pragma unroll
    for (int i = 0; i < 32; ++i) {
      const float4 v = *(const float4*)&r[i * 4];
      s += v.x * v.x + v.y * v.y + v.z * v.z + v.w * v.w;
    }
    cn_all[row] = s;
  } else {
    if (t < 64) {
      const float* r = ccb + (size_t)t * DD;
      float s = 0.f;
#pragma unroll
      for (int i = 0; i < 32; ++i) {
        const float4 v = *(const float4*)&r[i * 4];
        s += v.x * v.x + v.y * v.y + v.z * v.z + v.w * v.w;
      }
      cn_c[t] = s;
    }
  }
}

// ---- KG: merged GEMM (N=256 = Wc|Wfx) + LN + coarse VQ + p2a ---------------
// BM=32, BN=256, BK=64, 8 waves (512 thr), grid 256, gload_lds 2-phase dbuf.
// LDS per buffer: A[32][64]bf16 linear-swizzled (4KB) + B[256][64] (32KB).
__global__ __launch_bounds__(512) void kG(
    const unsigned short* __restrict__ xbf, const unsigned short* __restrict__ Wcomb,
    const unsigned short* __restrict__ ccbbf, const float* __restrict__ ccb,
    const float* __restrict__ bc, const float* __restrict__ gc,
    const float* __restrict__ betac, const float* __restrict__ cn_c,
    float* __restrict__ out0, unsigned short* __restrict__ zcq_bf,
    int* __restrict__ ci_g, int* __restrict__ counts,
    float* __restrict__ coarse_partial, float* __restrict__ p2a)
{
  extern __shared__ char smem[];
  const int t = threadIdx.x, lane = t & 63, wid = t >> 6;
  const int l15 = lane & 15, lhi = lane >> 4;
  const int m0 = blockIdx.x * 32;

  f32x4 acc[2][2];
#pragma unroll
  for (int m = 0; m < 2; ++m)
#pragma unroll
    for (int n = 0; n < 2; ++n) acc[m][n] = (f32x4){0.f, 0.f, 0.f, 0.f};

  // STAGE: per wave. A: waves 0-3 (1 KB issue each). B: all waves, 4 issues.
  // LDS linear; global source column pre-swizzled by ((row&7)<<4) XOR.
#define STAGE(bufoff, kt)                                                      \
  {                                                                            \
    if (wid < 4) {                                                             \
      const int ar = (wid << 3) + (lane >> 3);                                 \
      const char* asrc = (const char*)xbf +                                    \
          (((size_t)(m0 + ar) * HD + (size_t)(kt) * 64) << 1) +                \
          (((lane & 7) << 4) ^ ((ar & 7) << 4));                               \
      gload_lds16(asrc, smem + (bufoff) + (wid << 10));                        \
    }                                                                          \
    _Pragma("unroll")                                                          \
    for (int j = 0; j < 4; ++j) {                                              \
      const int br = (wid << 5) + (j << 3) + (lane >> 3);                      \
      const char* bsrc = (const char*)Wcomb +                                  \
          (((size_t)br * HD + (size_t)(kt) * 64) << 1) +                       \
          (((lane & 7) << 4) ^ ((br & 7) << 4));                               \
      gload_lds16(bsrc, smem + (bufoff) + 4096 + ((((wid << 5) + (j << 3))) << 7)); \
    }                                                                          \
  }

  int cur = 0;
  STAGE(0, 0);
  __syncthreads();
  for (int kt = 0; kt < 16; ++kt) {
    if (kt < 15) STAGE((cur ^ 1) * 36864, kt + 1);
    const char* bufA = smem + cur * 36864;
    const char* bufB = bufA + 4096;
#pragma unroll
    for (int ks = 0; ks < 2; ++ks) {
      const int kb = (ks << 6) + (lhi << 4);
      const int sa = kb ^ ((l15 & 7) << 4);
      bf16x8 a0 = *(const bf16x8*)(bufA + (l15 << 7) + sa);
      bf16x8 a1 = *(const bf16x8*)(bufA + ((l15 + 16) << 7) + sa);
#pragma unroll
      for (int n = 0; n < 2; ++n) {
        const int rb = (wid << 5) + (n << 4) + l15;
        bf16x8 b = *(const bf16x8*)(bufB + (rb << 7) + (kb ^ ((rb & 7) << 4)));
        acc[0][n] = __builtin_amdgcn_mfma_f32_16x16x32_bf16(a0, b, acc[0][n], 0, 0, 0);
        acc[1][n] = __builtin_amdgcn_mfma_f32_16x16x32_bf16(a1, b, acc[1][n], 0, 0, 0);
      }
    }
    __syncthreads();
    cur ^= 1;
  }
#undef STAGE

  // ---- epilogue (LDS overlay; all K-loop reads complete) ----
  float* zcf          = (float*)smem;                     // [32][132] f32
  unsigned short* cbb = (unsigned short*)(smem + 16896);  // [64][136] bf16
  unsigned short* zbb = (unsigned short*)(smem + 34304);  // [32][136] bf16
  float* zn  = (float*)(smem + 43008);                    // [32]
  float* cnS = (float*)(smem + 43136);                    // [64]
  float* dmS = (float*)(smem + 43392);                    // [4][32]
  int*   imS = (int*)  (smem + 43904);                    // [4][32]
  int*   cxS = (int*)  (smem + 44416);                    // [32]

  if (wid < 4) {   // cols 0..127 -> z_c (+bias) in LDS
#pragma unroll
    for (int m = 0; m < 2; ++m)
#pragma unroll
      for (int n = 0; n < 2; ++n)
#pragma unroll
        for (int r = 0; r < 4; ++r) {
          int row = (m << 4) + (lhi << 2) + r;
          int col = (wid << 5) + (n << 4) + l15;
          zcf[row * 132 + col] = acc[m][n][r] + bc[col];
        }
  } else {         // cols 128..255 -> GEMM2a partial to global
#pragma unroll
    for (int m = 0; m < 2; ++m)
#pragma unroll
      for (int n = 0; n < 2; ++n)
#pragma unroll
        for (int r = 0; r < 4; ++r) {
          int row = (m << 4) + (lhi << 2) + r;
          int col = ((wid - 4) << 5) + (n << 4) + l15;
          p2a[(size_t)(m0 + row) * DD + col] = acc[m][n][r];
        }
  }
#pragma unroll
  for (int i = 0; i < 2; ++i) {   // stage coarse codebook bf16
    int idx = t + i * 512;
    int row = idx >> 4, c8 = (idx & 15) << 3;
    *(uint4*)&cbb[row * 136 + c8] = *(const uint4*)&ccbbf[(row << 7) + c8];
  }
  if (t < 64) cnS[t] = cn_c[t];
  __syncthreads();
  {  // LayerNorm: 16 thr/row; capture ||z||^2; z -> bf16 LDS
    const int r = t >> 4, p = t & 15;
    float v[8];
    const float4 u0 = *(const float4*)&zcf[r * 132 + (p << 3)];
    const float4 u1 = *(const float4*)&zcf[r * 132 + (p << 3) + 4];
    v[0]=u0.x; v[1]=u0.y; v[2]=u0.z; v[3]=u0.w; v[4]=u1.x; v[5]=u1.y; v[6]=u1.z; v[7]=u1.w;
    float s = 0.f, s2 = 0.f;
#pragma unroll
    for (int j = 0; j < 8; ++j) { s += v[j]; s2 += v[j] * v[j]; }
#pragma unroll
    for (int off = 1; off < 16; off <<= 1) { s += __shfl_xor(s, off); s2 += __shfl_xor(s2, off); }
    const float mu   = s * (1.f / 128.f);
    const float rstd = rsqrtf(s2 * (1.f / 128.f) - mu * mu + 1e-5f);
    float s2n = 0.f;
#pragma unroll
    for (int j = 0; j < 8; ++j) {
      int col = (p << 3) + j;
      float vv = (v[j] - mu) * rstd * gc[col] + betac[col];
      v[j] = vv; s2n += vv * vv;
    }
#pragma unroll
    for (int off = 1; off < 16; off <<= 1) s2n += __shfl_xor(s2n, off);
    if (p == 0) zn[r] = s2n;
    *(uint4*)&zbb[r * 136 + (p << 3)] =
        make_uint4(pack2(v[0], v[1]), pack2(v[2], v[3]), pack2(v[4], v[5]), pack2(v[6], v[7]));
  }
  __syncthreads();
  {  // coarse distances via MFMA: wave = (codegrp cg, zrowgrp zg)
    const int cg = wid & 3, zg = wid >> 2;
    f32x4 dacc = (f32x4){0.f, 0.f, 0.f, 0.f};
#pragma unroll
    for (int ks = 0; ks < 4; ++ks) {
      const int lk = (ks << 5) + (lhi << 3);
      bf16x8 a = *(const bf16x8*)&cbb[((cg << 4) + l15) * 136 + lk];
      bf16x8 b = *(const bf16x8*)&zbb[((zg << 4) + l15) * 136 + lk];
      dacc = __builtin_amdgcn_mfma_f32_16x16x32_bf16(a, b, dacc, 0, 0, 0);
    }
    float bd = 3.4e38f; int bi = 0;
#pragma unroll
    for (int r = 0; r < 4; ++r) {
      int code = (cg << 4) + (lhi << 2) + r;
      float d = cnS[code] - 2.f * dacc[r];
      if (d < bd || (d == bd && code < bi)) { bd = d; bi = code; }
    }
#pragma unroll
    for (int off = 16; off < 64; off <<= 1) {
      float od = __shfl_xor(bd, off); int oi = __shfl_xor(bi, off);
      if (od < bd || (od == bd && oi < bi)) { bd = od; bi = oi; }
    }
    if (lhi == 0) { dmS[cg * 32 + (zg << 4) + l15] = bd; imS[cg * 32 + (zg << 4) + l15] = bi; }
  }
  __syncthreads();
  if (t < 32) {
    float bd = dmS[t]; int bi = imS[t];
#pragma unroll
    for (int w = 1; w < 4; ++w) {
      float od = dmS[w * 32 + t]; int oi = imS[w * 32 + t];
      if (od < bd || (od == bd && oi < bi)) { bd = od; bi = oi; }
    }
    ci_g[m0 + t] = bi;
    atomicAdd(&counts[bi], 1);
    cxS[t] = bi;
    float lp = bd + zn[t];
#pragma unroll
    for (int off = 1; off < 32; off <<= 1) lp += __shfl_xor(lp, off);
    if (t == 0) coarse_partial[blockIdx.x] = lp;
  }
  __syncthreads();
  {  // outputs: zcq gather (f32 + bf16)
    const int r = t >> 4, p = t & 15;
    const int c = cxS[r];
    const float4 q0 = *(const float4*)&ccb[(c << 7) + (p << 3)];
    const float4 q1 = *(const float4*)&ccb[(c << 7) + (p << 3) + 4];
    *(float4*)&out0[(size_t)(m0 + r) * DD + (p << 3)]     = q0;
    *(float4*)&out0[(size_t)(m0 + r) * DD + (p << 3) + 4] = q1;
    *(uint4*)&zcq_bf[(size_t)(m0 + r) * DD + (p << 3)] = *(const uint4*)&ccbbf[(c << 7) + (p << 3)];
  }
}

// ---- K2b: zf = LN(p2a + zcq @ Wfz^T + bias); store bf16 + ||zf||^2 --------
__global__ __launch_bounds__(256) void k2b(
    const unsigned short* __restrict__ zcq_bf, const unsigned short* __restrict__ Wfz,
    const float* __restrict__ p2a, const float* __restrict__ bfv,
    const float* __restrict__ gf, const float* __restrict__ betaf,
    unsigned short* __restrict__ zf_bf, float* __restrict__ zfn)
{
  extern __shared__ char smem[];
  unsigned short* Zq = (unsigned short*)smem;             // [32][136]
  unsigned short* Wz = (unsigned short*)(smem + 8704);    // [128][136]
  float* zff = (float*)smem;                              // [32][132] overlay

  const int t = threadIdx.x, lane = t & 63, wid = t >> 6;
  const int l15 = lane & 15, lhi = lane >> 4;
  const int m0 = blockIdx.x * 32;

#pragma unroll
  for (int i = 0; i < 2; ++i) {
    int idx = t + i * 256; int row = idx >> 4, c8 = (idx & 15) * 8;
    *(uint4*)&Zq[row * 136 + c8] = *(const uint4*)&zcq_bf[(size_t)(m0 + row) * DD + c8];
  }
#pragma unroll
  for (int i = 0; i < 8; ++i) {
    int idx = t + i * 256; int row = idx >> 4, c8 = (idx & 15) * 8;
    *(uint4*)&Wz[row * 136 + c8] = *(const uint4*)&Wfz[(size_t)row * DD + c8];
  }
  __syncthreads();
  f32x4 acc[2][2];
#pragma unroll
  for (int m = 0; m < 2; ++m)
#pragma unroll
    for (int n = 0; n < 2; ++n) acc[m][n] = (f32x4){0.f, 0.f, 0.f, 0.f};
#pragma unroll
  for (int ks = 0; ks < 4; ++ks) {
    const int lk = ks * 32 + lhi * 8;
    bf16x8 a0 = *(const bf16x8*)&Zq[l15 * 136 + lk];
    bf16x8 a1 = *(const bf16x8*)&Zq[(16 + l15) * 136 + lk];
#pragma unroll
    for (int n = 0; n < 2; ++n) {
      bf16x8 b = *(const bf16x8*)&Wz[(wid * 32 + n * 16 + l15) * 136 + lk];
      acc[0][n] = __builtin_amdgcn_mfma_f32_16x16x32_bf16(a0, b, acc[0][n], 0, 0, 0);
      acc[1][n] = __builtin_amdgcn_mfma_f32_16x16x32_bf16(a1, b, acc[1][n], 0, 0, 0);
    }
  }
  __syncthreads();
#pragma unroll
  for (int m = 0; m < 2; ++m)
#pragma unroll
    for (int n = 0; n < 2; ++n)
#pragma unroll
      for (int r = 0; r < 4; ++r) {
        int row = m * 16 + lhi * 4 + r;
        int col = wid * 32 + n * 16 + l15;
        zff[row * 132 + col] = acc[m][n][r] + p2a[(size_t)(m0 + row) * DD + col] + bfv[col];
      }
  __syncthreads();
  {  // LN: 8 threads/row, 16 cols each
    const int r = t >> 3, p = t & 7;
    float v[16];
#pragma unroll
    for (int q = 0; q < 4; ++q) {
      const float4 u = *(const float4*)&zff[r * 132 + p * 16 + q * 4];
      v[q * 4] = u.x; v[q * 4 + 1] = u.y; v[q * 4 + 2] = u.z; v[q * 4 + 3] = u.w;
    }
    float s = 0.f, s2 = 0.f;
#pragma unroll
    for (int j = 0; j < 16; ++j) { s += v[j]; s2 += v[j] * v[j]; }
#pragma unroll
    for (int off = 1; off < 8; off <<= 1) { s += __shfl_xor(s, off); s2 += __shfl_xor(s2, off); }
    const float mu   = s * (1.f / 128.f);
    const float rstd = rsqrtf(s2 * (1.f / 128.f) - mu * mu + 1e-5f);
    float s2n = 0.f;
    unsigned int o[8];
#pragma unroll
    for (int jj = 0; jj < 8; ++jj) {
      int col = p * 16 + 2 * jj;
      float v0 = (v[2 * jj]     - mu) * rstd * gf[col]     + betaf[col];
      float v1 = (v[2 * jj + 1] - mu) * rstd * gf[col + 1] + betaf[col + 1];
      s2n += v0 * v0 + v1 * v1;
      o[jj] = pack2(v0, v1);
    }
#pragma unroll
    for (int off = 1; off < 8; off <<= 1) s2n += __shfl_xor(s2n, off);
    if (p == 0) zfn[m0 + r] = s2n;
    *(uint4*)&zf_bf[(size_t)(m0 + r) * DD + p * 16]     = make_uint4(o[0], o[1], o[2], o[3]);
    *(uint4*)&zf_bf[(size_t)(m0 + r) * DD + p * 16 + 8] = make_uint4(o[4], o[5], o[6], o[7]);
  }
}

// ---- bucketing ------------------------------------------------------------
__global__ void k_prefix(const int* __restrict__ counts, int* __restrict__ offsets,
                         int* __restrict__ cursor) {
  if (threadIdx.x == 0) {
    int run = 0;
    for (int g = 0; g < NK0; ++g) { offsets[g] = run; cursor[g] = run; run += counts[g]; }
  }
}
__global__ void k_scatter(const int* __restrict__ ci_g, int* __restrict__ cursor,
                          int* __restrict__ bucket_rows) {
  int i = blockIdx.x * 256 + threadIdx.x;
  int pos = atomicAdd(&cursor[ci_g[i]], 1);
  bucket_rows[pos] = i;
}

// ---- K3: per-(chunk,group) fine VQ ----------------------------------------
__global__ __launch_bounds__(256) void k3_fine(
    const unsigned short* __restrict__ zf_bf, const unsigned short* __restrict__ fcbbf,
    const float* __restrict__ fcb, const float* __restrict__ cn_all,
    const float* __restrict__ zfn,
    const int* __restrict__ counts, const int* __restrict__ offsets,
    const int* __restrict__ bucket_rows,
    float* __restrict__ out1, float* __restrict__ fine_partial)
{
  extern __shared__ char smem[];
  unsigned short* Vb  = (unsigned short*)smem;            // [256][136]
  unsigned short* zfL = (unsigned short*)(smem + 69632);  // [32][136]
  int*   ridS = (int*)  (smem + 78336);                   // [32]
  float* dmS  = (float*)(smem + 78464);                   // [4][32]
  int*   imS  = (int*)  (smem + 78976);                   // [4][32]
  int*   fiS  = (int*)  (smem + 79488);                   // [32]

  const int g = blockIdx.y, cx = blockIdx.x;   // cx in [0,4)
  const int t = threadIdx.x, lane = t & 63, wid = t >> 6;
  const int l15 = lane & 15, lhi = lane >> 4;
  const int count = counts[g], start = offsets[g];

  float lp = 0.f;
  if (cx * 32 < count) {
#pragma unroll
    for (int i = 0; i < 16; ++i) {   // full 256x128 bf16 codebook
      int idx = t + i * 256; int row = idx >> 4, c8 = (idx & 15) * 8;
      *(uint4*)&Vb[row * 136 + c8] = *(const uint4*)&fcbbf[((size_t)g * NK1 + row) * DD + c8];
    }
    float cnr[4];
#pragma unroll
    for (int n = 0; n < 4; ++n) cnr[n] = cn_all[g * NK1 + wid * 64 + n * 16 + l15];

    for (int r0 = cx * 32; r0 < count; r0 += 128) {
      __syncthreads();
      if (t < 32) ridS[t] = (r0 + t < count) ? bucket_rows[start + r0 + t] : -1;
      __syncthreads();
#pragma unroll
      for (int i = 0; i < 2; ++i) {
        int idx = t + i * 256; int row = idx >> 4, c8 = (idx & 15) * 8;
        int rid = ridS[row];
        uint4 v = make_uint4(0u, 0u, 0u, 0u);
        if (rid >= 0) v = *(const uint4*)&zf_bf[(size_t)rid * DD + c8];
        *(uint4*)&zfL[row * 136 + c8] = v;
      }
      __syncthreads();
      f32x4 acc[2][4];
#pragma unroll
      for (int m = 0; m < 2; ++m)
#pragma unroll
        for (int n = 0; n < 4; ++n) acc[m][n] = (f32x4){0.f, 0.f, 0.f, 0.f};
#pragma unroll
      for (int ks = 0; ks < 4; ++ks) {
        const int lk = ks * 32 + lhi * 8;
        bf16x8 a0 = *(const bf16x8*)&zfL[l15 * 136 + lk];
        bf16x8 a1 = *(const bf16x8*)&zfL[(16 + l15) * 136 + lk];
#pragma unroll
        for (int n = 0; n < 4; ++n) {
          bf16x8 b = *(const bf16x8*)&Vb[(wid * 64 + n * 16 + l15) * 136 + lk];
          acc[0][n] = __builtin_amdgcn_mfma_f32_16x16x32_bf16(a0, b, acc[0][n], 0, 0, 0);
          acc[1][n] = __builtin_amdgcn_mfma_f32_16x16x32_bf16(a1, b, acc[1][n], 0, 0, 0);
        }
      }
#pragma unroll
      for (int m = 0; m < 2; ++m)
#pragma unroll
        for (int r = 0; r < 4; ++r) {
          float bd = 3.4e38f; int bi = 0;
#pragma unroll
          for (int n = 0; n < 4; ++n) {
            int code = wid * 64 + n * 16 + l15;
            float d = cnr[n] - 2.f * acc[m][n][r];
            if (d < bd || (d == bd && code < bi)) { bd = d; bi = code; }
          }
#pragma unroll
          for (int off = 1; off < 16; off <<= 1) {
            float od = __shfl_xor(bd, off); int oi = __shfl_xor(bi, off);
            if (od < bd || (od == bd && oi < bi)) { bd = od; bi = oi; }
          }
          if (l15 == 0) {
            int row = m * 16 + lhi * 4 + r;
            dmS[wid * 32 + row] = bd; imS[wid * 32 + row] = bi;
          }
        }
      __syncthreads();
      if (t < 32) {
        float bd = dmS[t]; int bi = imS[t];
#pragma unroll
        for (int w = 1; w < 4; ++w) {
          float od = dmS[w * 32 + t]; int oi = imS[w * 32 + t];
          if (od < bd || (od == bd && oi < bi)) { bd = od; bi = oi; }
        }
        fiS[t] = bi;
        int rid = ridS[t];
        if (rid >= 0) lp += bd + zfn[rid];
      }
      __syncthreads();
      {  // zfq output (float4-vectorized)
        const int r = t >> 3, p = t & 7;
        const int rid = ridS[r];
        if (rid >= 0) {
          const int fi = fiS[r];
          const float* qr = &fcb[((size_t)g * NK1 + fi) * DD + p * 16];
          float* orow = &out1[(size_t)rid * DD + p * 16];
#pragma unroll
          for (int q = 0; q < 4; ++q) *(float4*)&orow[q * 4] = *(const float4*)&qr[q * 4];
        }
      }
    }
  }
#pragma unroll
  for (int off = 1; off < 32; off <<= 1) lp += __shfl_xor(lp, off);
  if (t == 0) fine_partial[g * 4 + cx] = lp;
}

// ---- K4: loss reduce (one wave) -------------------------------------------
__global__ void k_final(const float* __restrict__ coarse_partial,
                        const float* __restrict__ fine_partial,
                        float* __restrict__ outL) {
  const int t = threadIdx.x;
  float s = 0.f;
#pragma unroll
  for (int i = 0; i < 4; ++i) s += coarse_partial[t + i * 64];
#pragma unroll
  for (int i = 0; i < 4; ++i) s += fine_partial[t + i * 64];
#pragma unroll
  for (int off = 1; off < 64; off <<= 1) s += __shfl_xor(s, off);
  if (t == 0) outL[0] = 1.25f * s / 1048576.0f;
}

// ---- launcher -------------------------------------------------------------
extern "C" void kernel_launch(void* const* d_in, const int* in_sizes, int n_in,
                              void* d_out, int out_size, void* d_ws, size_t ws_size,
                              hipStream_t stream) {
  const float* x     = (const float*)d_in[0];
  const float* Wc    = (const float*)d_in[1];
  const float* bc    = (const float*)d_in[2];
  const float* gc    = (const float*)d_in[3];
  const float* betac = (const float*)d_in[4];
  const float* ccb   = (const float*)d_in[5];
  const float* Wf    = (const float*)d_in[6];
  const float* bfv   = (const float*)d_in[7];
  const float* gf    = (const float*)d_in[8];
  const float* betaf = (const float*)d_in[9];
  const float* fcb   = (const float*)d_in[10];

  float* out0 = (float*)d_out;
  float* out1 = out0 + (size_t)NB * DD;
  float* outL = out0 + (size_t)2 * NB * DD;

  char* ws = (char*)d_ws;
  unsigned short* xbf    = (unsigned short*)(ws);
  unsigned short* Wcomb  = (unsigned short*)(ws + 16777216);
  unsigned short* Wfz    = (unsigned short*)(ws + 17301504);
  unsigned short* fcbbf  = (unsigned short*)(ws + 17334272);
  unsigned short* ccbbf  = (unsigned short*)(ws + 21528576);
  float*          cn_all = (float*)(ws + 21544960);
  float*          cn_c   = (float*)(ws + 21610496);
  float*          p2a    = (float*)(ws + 21610752);
  unsigned short* zcq_bf = (unsigned short*)(ws + 25805056);
  unsigned short* zf_bf  = (unsigned short*)(ws + 27902208);
  float*          zfn    = (float*)(ws + 29999360);
  int* ci_g        = (int*)(ws + 30032128);
  int* bucket_rows = (int*)(ws + 30064896);
  int* counts      = (int*)(ws + 30097664);
  int* offsets     = (int*)(ws + 30097920);
  int* cursor      = (int*)(ws + 30098176);
  float* coarse_partial = (float*)(ws + 30098432);
  float* fine_partial   = (float*)(ws + 30099456);

  hipFuncSetAttribute(reinterpret_cast<const void*>(kG),
                      hipFuncAttributeMaxDynamicSharedMemorySize, 73728);
  hipFuncSetAttribute(reinterpret_cast<const void*>(k2b),
                      hipFuncAttributeMaxDynamicSharedMemorySize, 43520);
  hipFuncSetAttribute(reinterpret_cast<const void*>(k3_fine),
                      hipFuncAttributeMaxDynamicSharedMemorySize, 79616);

  hipMemsetAsync(ws + 30097664, 0, 768, stream);

  hipLaunchKernelGGL(k0_convert, dim3(5325), dim3(256), 0, stream,
                     x, Wc, Wf, fcb, ccb, xbf, Wcomb, Wfz, fcbbf, ccbbf, cn_all, cn_c);
  hipLaunchKernelGGL(kG, dim3(256), dim3(512), 73728, stream,
                     xbf, Wcomb, ccbbf, ccb, bc, gc, betac, cn_c,
                     out0, zcq_bf, ci_g, counts, coarse_partial, p2a);
  hipLaunchKernelGGL(k2b, dim3(256), dim3(256), 43520, stream,
                     zcq_bf, Wfz, p2a, bfv, gf, betaf, zf_bf, zfn);
  hipLaunchKernelGGL(k_prefix, dim3(1), dim3(64), 0, stream, counts, offsets, cursor);
  hipLaunchKernelGGL(k_scatter, dim3(NB / 256), dim3(256), 0, stream, ci_g, cursor, bucket_rows);
  hipLaunchKernelGGL(k3_fine, dim3(4, 64), dim3(256), 79616, stream,
                     zf_bf, fcbbf, fcb, cn_all, zfn, counts, offsets, bucket_rows,
                     out1, fine_partial);
  hipLaunchKernelGGL(k_final, dim3(1), dim3(64), 0, stream, coarse_partial, fine_partial, outL);
}

// Round 5
// 62.270 us; speedup vs baseline: 2.3749x; 1.5810x over previous
//
#include <hip/hip_runtime.h>

#define NB   8192
#define HD   1024
#define HFD  1152
#define NK0  64
#define NK1  256
#define DD   128

typedef __attribute__((ext_vector_type(4))) float  f32x4;
typedef __attribute__((ext_vector_type(8))) __bf16 bf16x8;

__device__ __forceinline__ unsigned short f2bf(float f) {
  unsigned int u = __float_as_uint(f);
  u += 0x7fffu + ((u >> 16) & 1u);
  return (unsigned short)(u >> 16);
}
__device__ __forceinline__ unsigned int pack2(float a, float b) {
  return (unsigned int)f2bf(a) | ((unsigned int)f2bf(b) << 16);
}
__device__ __forceinline__ uint4 pack8(const float4 a, const float4 b) {
  return make_uint4(pack2(a.x, a.y), pack2(a.z, a.w), pack2(b.x, b.y), pack2(b.z, b.w));
}
__device__ __forceinline__ void gload_lds16(const void* g, void* l) {
  __builtin_amdgcn_global_load_lds(
      (const __attribute__((address_space(1))) void*)g,
      (__attribute__((address_space(3))) void*)l, 16, 0, 0);
}

// ---- K0: weight/codebook conversions + norms (x handled in kG) ------------
// blocks: [0,64) Wc->Wcomb[0:128] | [64,136) Wf->Wcomb[128:256]+Wfz
//         [136,1160) fcb | [1160,1164) ccb | [1164,1228) fine norms | [1228] coarse norms
__global__ __launch_bounds__(256) void k0_convert(
    const float* __restrict__ Wc, const float* __restrict__ Wf,
    const float* __restrict__ fcb, const float* __restrict__ ccb,
    unsigned short* __restrict__ Wcomb, unsigned short* __restrict__ Wfz,
    unsigned short* __restrict__ fcbbf, unsigned short* __restrict__ ccbbf,
    float* __restrict__ cn_all, float* __restrict__ cn_c)
{
  const int bid = blockIdx.x, t = threadIdx.x;
  if (bid < 64) {
    long e0 = ((long)bid * 256 + t) * 8;
    const float4 a = *(const float4*)&Wc[e0];
    const float4 b = *(const float4*)&Wc[e0 + 4];
    *(uint4*)&Wcomb[e0] = pack8(a, b);
  } else if (bid < 136) {
    long e0 = ((long)(bid - 64) * 256 + t) * 8;
    const float4 a = *(const float4*)&Wf[e0];
    const float4 b = *(const float4*)&Wf[e0 + 4];
    const uint4 pk = pack8(a, b);
    const int row = (int)(e0 / HFD), c = (int)(e0 % HFD);
    if (c < 1024) *(uint4*)&Wcomb[(size_t)(128 + row) * HD + c] = pk;
    else          *(uint4*)&Wfz[(size_t)row * DD + (c - 1024)] = pk;
  } else if (bid < 1160) {
    long e0 = ((long)(bid - 136) * 256 + t) * 8;
    const float4 a = *(const float4*)&fcb[e0];
    const float4 b = *(const float4*)&fcb[e0 + 4];
    *(uint4*)&fcbbf[e0] = pack8(a, b);
  } else if (bid < 1164) {
    long e0 = ((long)(bid - 1160) * 256 + t) * 8;
    const float4 a = *(const float4*)&ccb[e0];
    const float4 b = *(const float4*)&ccb[e0 + 4];
    *(uint4*)&ccbbf[e0] = pack8(a, b);
  } else if (bid < 1228) {
    const int row = (bid - 1164) * 256 + t;
    const float* r = fcb + (size_t)row * DD;
    float s = 0.f;
#pragma unroll
    for (int i = 0; i < 32; ++i) {
      const float4 v = *(const float4*)&r[i * 4];
      s += v.x * v.x + v.y * v.y + v.z * v.z + v.w * v.w;
    }
    cn_all[row] = s;
  } else {
    if (t < 64) {
      const float* r = ccb + (size_t)t * DD;
      float s = 0.f;
#pragma unroll
      for (int i = 0; i < 32; ++i) {
        const float4 v = *(const float4*)&r[i * 4];
        s += v.x * v.x + v.y * v.y + v.z * v.z + v.w * v.w;
      }
      cn_c[t] = s;
    }
  }
}

// ---- KG: merged GEMM (N=256) + LN + coarse VQ + fused k2b (zf) -------------
// BM=32, BN=256, BK=64, 8 waves (512 thr), grid 256, dbuf.
// A: f32 x -> reg -> cvt -> swizzled ds_write. B: gload_lds from Wcomb.
__global__ __launch_bounds__(512) void kG(
    const float* __restrict__ x, const unsigned short* __restrict__ Wcomb,
    const unsigned short* __restrict__ ccbbf, const float* __restrict__ ccb,
    const float* __restrict__ bc, const float* __restrict__ gc,
    const float* __restrict__ betac, const float* __restrict__ cn_c,
    const float* __restrict__ bfv, const float* __restrict__ gf,
    const float* __restrict__ betaf, const unsigned short* __restrict__ Wfz,
    float* __restrict__ out0, unsigned short* __restrict__ zf_bf,
    float* __restrict__ zfn, int* __restrict__ ci_g,
    float* __restrict__ coarse_partial)
{
  extern __shared__ char smem[];
  const int t = threadIdx.x, lane = t & 63, wid = t >> 6;
  const int l15 = lane & 15, lhi = lane >> 4;
  const int m0 = blockIdx.x * 32;

  f32x4 acc[2][2];
#pragma unroll
  for (int m = 0; m < 2; ++m)
#pragma unroll
    for (int n = 0; n < 2; ++n) acc[m][n] = (f32x4){0.f, 0.f, 0.f, 0.f};

  const int axr = t >> 4;           // A staging: row 0..31
  const int axc = (t & 15) << 2;    // f32 col 0..60
  float4 ra;

#define LOADA(kt) ra = *(const float4*)&x[(size_t)(m0 + axr) * HD + (size_t)(kt) * 64 + axc];
#define WRITEA(bufoff)                                                          \
  {                                                                             \
    *(uint2*)(smem + (bufoff) + (axr << 7) + ((((t & 15) << 3)) ^ ((axr & 7) << 4))) = \
        make_uint2(pack2(ra.x, ra.y), pack2(ra.z, ra.w));                       \
  }
#define STAGEB(bufoff, kt)                                                      \
  {                                                                             \
    _Pragma("unroll")                                                           \
    for (int j = 0; j < 4; ++j) {                                               \
      const int br = (wid << 5) + (j << 3) + (lane >> 3);                       \
      const char* bsrc = (const char*)Wcomb +                                   \
          (((size_t)br * HD + (size_t)(kt) * 64) << 1) +                        \
          (((lane & 7) << 4) ^ ((br & 7) << 4));                                \
      gload_lds16(bsrc, smem + (bufoff) + 4096 + (((wid << 5) + (j << 3)) << 7)); \
    }                                                                           \
  }

  // prologue: buf0 <- tile 0; preload A(1)
  LOADA(0);
  WRITEA(0);
  STAGEB(0, 0);
  LOADA(1);
  __syncthreads();

  int cur = 0;
  for (int kt = 0; kt < 16; ++kt) {
    const int nxt = (cur ^ 1) * 36864;
    if (kt < 15) { WRITEA(nxt); STAGEB(nxt, kt + 1); }
    if (kt < 14) LOADA(kt + 2);
    const char* bufA = smem + cur * 36864;
    const char* bufB = bufA + 4096;
#pragma unroll
    for (int ks = 0; ks < 2; ++ks) {
      const int kb = (ks << 6) + (lhi << 4);
      const int sa = kb ^ ((l15 & 7) << 4);
      bf16x8 a0 = *(const bf16x8*)(bufA + (l15 << 7) + sa);
      bf16x8 a1 = *(const bf16x8*)(bufA + ((l15 + 16) << 7) + sa);
#pragma unroll
      for (int n = 0; n < 2; ++n) {
        const int rb = (wid << 5) + (n << 4) + l15;
        bf16x8 b = *(const bf16x8*)(bufB + (rb << 7) + (kb ^ ((rb & 7) << 4)));
        acc[0][n] = __builtin_amdgcn_mfma_f32_16x16x32_bf16(a0, b, acc[0][n], 0, 0, 0);
        acc[1][n] = __builtin_amdgcn_mfma_f32_16x16x32_bf16(a1, b, acc[1][n], 0, 0, 0);
      }
    }
    __syncthreads();
    cur ^= 1;
  }
#undef LOADA
#undef WRITEA
#undef STAGEB

  // ---- epilogue LDS overlay ----
  int*   cxS = (int*)  smem;                              // [32]      (E4-)
  unsigned short* zqb = (unsigned short*)(smem + 128);    // [32][136] (E5-)
  float* zcf          = (float*)smem;                     // [32][132] (E1-E2)
  float* zff          = (float*)(smem + 16896);           // [32][132] (E1-E7)
  unsigned short* cbb = (unsigned short*)(smem + 33792);  // [64][136] (E1-E3)
  unsigned short* Wz  = (unsigned short*)(smem + 33792);  // [128][136](E5-E6)
  unsigned short* zbb = (unsigned short*)(smem + 51200);  // [32][136] (E2-E3)
  float* zn  = (float*)(smem + 59904);                    // [32]
  float* cnS = (float*)(smem + 60032);                    // [64]
  float* dmS = (float*)(smem + 60288);                    // [4][32]
  int*   imS = (int*)  (smem + 60800);                    // [4][32]

  // E1: distribute acc; stage coarse codebook
  if (wid < 4) {
#pragma unroll
    for (int m = 0; m < 2; ++m)
#pragma unroll
      for (int n = 0; n < 2; ++n)
#pragma unroll
        for (int r = 0; r < 4; ++r) {
          int row = (m << 4) + (lhi << 2) + r;
          int col = (wid << 5) + (n << 4) + l15;
          zcf[row * 132 + col] = acc[m][n][r] + bc[col];
        }
  } else {
#pragma unroll
    for (int m = 0; m < 2; ++m)
#pragma unroll
      for (int n = 0; n < 2; ++n)
#pragma unroll
        for (int r = 0; r < 4; ++r) {
          int row = (m << 4) + (lhi << 2) + r;
          int col = ((wid - 4) << 5) + (n << 4) + l15;
          zff[row * 132 + col] = acc[m][n][r] + bfv[col];
        }
  }
#pragma unroll
  for (int i = 0; i < 2; ++i) {
    int idx = t + i * 512;
    int row = idx >> 4, c8 = (idx & 15) << 3;
    *(uint4*)&cbb[row * 136 + c8] = *(const uint4*)&ccbbf[(row << 7) + c8];
  }
  if (t < 64) cnS[t] = cn_c[t];
  __syncthreads();

  // E2: LayerNorm(z_c); capture ||z||^2; z -> bf16
  {
    const int r = t >> 4, p = t & 15;
    float v[8];
    const float4 u0 = *(const float4*)&zcf[r * 132 + (p << 3)];
    const float4 u1 = *(const float4*)&zcf[r * 132 + (p << 3) + 4];
    v[0]=u0.x; v[1]=u0.y; v[2]=u0.z; v[3]=u0.w; v[4]=u1.x; v[5]=u1.y; v[6]=u1.z; v[7]=u1.w;
    float s = 0.f, s2 = 0.f;
#pragma unroll
    for (int j = 0; j < 8; ++j) { s += v[j]; s2 += v[j] * v[j]; }
#pragma unroll
    for (int off = 1; off < 16; off <<= 1) { s += __shfl_xor(s, off); s2 += __shfl_xor(s2, off); }
    const float mu   = s * (1.f / 128.f);
    const float rstd = rsqrtf(s2 * (1.f / 128.f) - mu * mu + 1e-5f);
    float s2n = 0.f;
#pragma unroll
    for (int j = 0; j < 8; ++j) {
      int col = (p << 3) + j;
      float vv = (v[j] - mu) * rstd * gc[col] + betac[col];
      v[j] = vv; s2n += vv * vv;
    }
#pragma unroll
    for (int off = 1; off < 16; off <<= 1) s2n += __shfl_xor(s2n, off);
    if (p == 0) zn[r] = s2n;
    *(uint4*)&zbb[r * 136 + (p << 3)] =
        make_uint4(pack2(v[0], v[1]), pack2(v[2], v[3]), pack2(v[4], v[5]), pack2(v[6], v[7]));
  }
  __syncthreads();

  // E3: coarse distances via MFMA (cg = code grp, zg = z-row grp)
  {
    const int cg = wid & 3, zg = wid >> 2;
    f32x4 dacc = (f32x4){0.f, 0.f, 0.f, 0.f};
#pragma unroll
    for (int ks = 0; ks < 4; ++ks) {
      const int lk = (ks << 5) + (lhi << 3);
      bf16x8 a = *(const bf16x8*)&cbb[((cg << 4) + l15) * 136 + lk];
      bf16x8 b = *(const bf16x8*)&zbb[((zg << 4) + l15) * 136 + lk];
      dacc = __builtin_amdgcn_mfma_f32_16x16x32_bf16(a, b, dacc, 0, 0, 0);
    }
    float bd = 3.4e38f; int bi = 0;
#pragma unroll
    for (int r = 0; r < 4; ++r) {
      int code = (cg << 4) + (lhi << 2) + r;
      float d = cnS[code] - 2.f * dacc[r];
      if (d < bd || (d == bd && code < bi)) { bd = d; bi = code; }
    }
#pragma unroll
    for (int off = 16; off < 64; off <<= 1) {
      float od = __shfl_xor(bd, off); int oi = __shfl_xor(bi, off);
      if (od < bd || (od == bd && oi < bi)) { bd = od; bi = oi; }
    }
    if (lhi == 0) { dmS[cg * 32 + (zg << 4) + l15] = bd; imS[cg * 32 + (zg << 4) + l15] = bi; }
  }
  __syncthreads();

  // E4: final coarse argmin + loss partial + ci
  if (t < 32) {
    float bd = dmS[t]; int bi = imS[t];
#pragma unroll
    for (int w = 1; w < 4; ++w) {
      float od = dmS[w * 32 + t]; int oi = imS[w * 32 + t];
      if (od < bd || (od == bd && oi < bi)) { bd = od; bi = oi; }
    }
    ci_g[m0 + t] = bi;
    cxS[t] = bi;
    float lp = bd + zn[t];
#pragma unroll
    for (int off = 1; off < 32; off <<= 1) lp += __shfl_xor(lp, off);
    if (t == 0) coarse_partial[blockIdx.x] = lp;
  }
  __syncthreads();

  // E5: stage Wfz + zcq(bf16) tiles; write out0 (zcq f32)
  {
#pragma unroll
    for (int i = 0; i < 4; ++i) {
      int idx = t + i * 512;
      int row = idx >> 4, c8 = (idx & 15) << 3;
      *(uint4*)&Wz[row * 136 + c8] = *(const uint4*)&Wfz[(row << 7) + c8];
    }
    const int r = t >> 4, p = t & 15;
    const int c = cxS[r];
    *(uint4*)&zqb[r * 136 + (p << 3)] = *(const uint4*)&ccbbf[(c << 7) + (p << 3)];
    const float4 q0 = *(const float4*)&ccb[(c << 7) + (p << 3)];
    const float4 q1 = *(const float4*)&ccb[(c << 7) + (p << 3) + 4];
    *(float4*)&out0[(size_t)(m0 + r) * DD + (p << 3)]     = q0;
    *(float4*)&out0[(size_t)(m0 + r) * DD + (p << 3) + 4] = q1;
  }
  __syncthreads();

  // E6: zff += zcq @ Wfz^T (wave wid owns cols wid*16..+15)
  {
    f32x4 a2[2];
    a2[0] = (f32x4){0.f, 0.f, 0.f, 0.f};
    a2[1] = (f32x4){0.f, 0.f, 0.f, 0.f};
#pragma unroll
    for (int ks = 0; ks < 4; ++ks) {
      const int lk = (ks << 5) + (lhi << 3);
      bf16x8 a0 = *(const bf16x8*)&zqb[l15 * 136 + lk];
      bf16x8 a1 = *(const bf16x8*)&zqb[(16 + l15) * 136 + lk];
      bf16x8 b  = *(const bf16x8*)&Wz[((wid << 4) + l15) * 136 + lk];
      a2[0] = __builtin_amdgcn_mfma_f32_16x16x32_bf16(a0, b, a2[0], 0, 0, 0);
      a2[1] = __builtin_amdgcn_mfma_f32_16x16x32_bf16(a1, b, a2[1], 0, 0, 0);
    }
#pragma unroll
    for (int m = 0; m < 2; ++m)
#pragma unroll
      for (int r = 0; r < 4; ++r)
        zff[((m << 4) + (lhi << 2) + r) * 132 + (wid << 4) + l15] += a2[m][r];
  }
  __syncthreads();

  // E7: LayerNorm(z_f) -> zf_bf + zfn
  {
    const int r = t >> 4, p = t & 15;
    float v[8];
    const float4 u0 = *(const float4*)&zff[r * 132 + (p << 3)];
    const float4 u1 = *(const float4*)&zff[r * 132 + (p << 3) + 4];
    v[0]=u0.x; v[1]=u0.y; v[2]=u0.z; v[3]=u0.w; v[4]=u1.x; v[5]=u1.y; v[6]=u1.z; v[7]=u1.w;
    float s = 0.f, s2 = 0.f;
#pragma unroll
    for (int j = 0; j < 8; ++j) { s += v[j]; s2 += v[j] * v[j]; }
#pragma unroll
    for (int off = 1; off < 16; off <<= 1) { s += __shfl_xor(s, off); s2 += __shfl_xor(s2, off); }
    const float mu   = s * (1.f / 128.f);
    const float rstd = rsqrtf(s2 * (1.f / 128.f) - mu * mu + 1e-5f);
    float s2n = 0.f;
    unsigned int o[4];
#pragma unroll
    for (int jj = 0; jj < 4; ++jj) {
      int col = (p << 3) + 2 * jj;
      float v0 = (v[2 * jj]     - mu) * rstd * gf[col]     + betaf[col];
      float v1 = (v[2 * jj + 1] - mu) * rstd * gf[col + 1] + betaf[col + 1];
      s2n += v0 * v0 + v1 * v1;
      o[jj] = pack2(v0, v1);
    }
#pragma unroll
    for (int off = 1; off < 16; off <<= 1) s2n += __shfl_xor(s2n, off);
    if (p == 0) zfn[m0 + r] = s2n;
    *(uint4*)&zf_bf[(size_t)(m0 + r) * DD + (p << 3)] = make_uint4(o[0], o[1], o[2], o[3]);
  }
}

// ---- K3: fine VQ; blocks self-select rows by scanning ci_g ----------------
__global__ __launch_bounds__(256) void k3_fine(
    const unsigned short* __restrict__ zf_bf, const unsigned short* __restrict__ fcbbf,
    const float* __restrict__ fcb, const float* __restrict__ cn_all,
    const float* __restrict__ zfn, const int* __restrict__ ci_g,
    float* __restrict__ out1, float* __restrict__ fine_partial)
{
  extern __shared__ char smem[];
  unsigned short* Vb  = (unsigned short*)smem;            // [256][136]
  unsigned short* zfL = (unsigned short*)(smem + 69632);  // [32][136]
  int*   list = (int*)  (smem + 78336);                   // [2048]
  int*   ridS = (int*)  (smem + 86528);                   // [32]
  float* dmS  = (float*)(smem + 86656);                   // [4][32]
  int*   imS  = (int*)  (smem + 87168);                   // [4][32]
  int*   fiS  = (int*)  (smem + 87680);                   // [32]
  int*   wsum = (int*)  (smem + 87808);                   // [8]

  const int g = blockIdx.y, cx = blockIdx.x;   // cx in [0,4)
  const int t = threadIdx.x, lane = t & 63, wid = t >> 6;
  const int l15 = lane & 15, lhi = lane >> 4;

  // --- deterministic compaction of {i : ci_g[i]==g} ---
  const int seg = t * 32;
  int mcount = 0;
#pragma unroll 8
  for (int q = 0; q < 32; ++q) mcount += (ci_g[seg + q] == g);
  int v = mcount;
#pragma unroll
  for (int off = 1; off < 64; off <<= 1) {
    int o = __shfl_up(v, off);
    if (lane >= off) v += o;
  }
  if (lane == 63) wsum[wid] = v;
  __syncthreads();
  if (t == 0) {
    int run = 0;
#pragma unroll
    for (int w = 0; w < 4; ++w) { int c = wsum[w]; wsum[w] = run; run += c; }
    wsum[4] = run;
  }
  __syncthreads();
  const int total = wsum[4];
  const int tcap = total > 2048 ? 2048 : total;
  {
    int j = wsum[wid] + v - mcount;
    for (int q = 0; q < 32; ++q) {
      if (ci_g[seg + q] == g) { if (j < 2048) list[j] = seg + q; ++j; }
    }
  }
  __syncthreads();

  float lp = 0.f;
  if (cx * 32 < tcap) {
#pragma unroll
    for (int i = 0; i < 16; ++i) {   // stage full group codebook bf16
      int idx = t + i * 256; int row = idx >> 4, c8 = (idx & 15) * 8;
      *(uint4*)&Vb[row * 136 + c8] = *(const uint4*)&fcbbf[((size_t)g * NK1 + row) * DD + c8];
    }
    float cnr[4];
#pragma unroll
    for (int n = 0; n < 4; ++n) cnr[n] = cn_all[g * NK1 + wid * 64 + n * 16 + l15];

    for (int r0 = cx * 32; r0 < tcap; r0 += 128) {
      __syncthreads();
      if (t < 32) ridS[t] = (r0 + t < tcap) ? list[r0 + t] : -1;
      __syncthreads();
#pragma unroll
      for (int i = 0; i < 2; ++i) {
        int idx = t + i * 256; int row = idx >> 4, c8 = (idx & 15) * 8;
        int rid = ridS[row];
        uint4 vv = make_uint4(0u, 0u, 0u, 0u);
        if (rid >= 0) vv = *(const uint4*)&zf_bf[(size_t)rid * DD + c8];
        *(uint4*)&zfL[row * 136 + c8] = vv;
      }
      __syncthreads();
      f32x4 acc[2][4];
#pragma unroll
      for (int m = 0; m < 2; ++m)
#pragma unroll
        for (int n = 0; n < 4; ++n) acc[m][n] = (f32x4){0.f, 0.f, 0.f, 0.f};
#pragma unroll
      for (int ks = 0; ks < 4; ++ks) {
        const int lk = ks * 32 + lhi * 8;
        bf16x8 a0 = *(const bf16x8*)&zfL[l15 * 136 + lk];
        bf16x8 a1 = *(const bf16x8*)&zfL[(16 + l15) * 136 + lk];
#pragma unroll
        for (int n = 0; n < 4; ++n) {
          bf16x8 b = *(const bf16x8*)&Vb[(wid * 64 + n * 16 + l15) * 136 + lk];
          acc[0][n] = __builtin_amdgcn_mfma_f32_16x16x32_bf16(a0, b, acc[0][n], 0, 0, 0);
          acc[1][n] = __builtin_amdgcn_mfma_f32_16x16x32_bf16(a1, b, acc[1][n], 0, 0, 0);
        }
      }
#pragma unroll
      for (int m = 0; m < 2; ++m)
#pragma unroll
        for (int r = 0; r < 4; ++r) {
          float bd = 3.4e38f; int bi = 0;
#pragma unroll
          for (int n = 0; n < 4; ++n) {
            int code = wid * 64 + n * 16 + l15;
            float d = cnr[n] - 2.f * acc[m][n][r];
            if (d < bd || (d == bd && code < bi)) { bd = d; bi = code; }
          }
#pragma unroll
          for (int off = 1; off < 16; off <<= 1) {
            float od = __shfl_xor(bd, off); int oi = __shfl_xor(bi, off);
            if (od < bd || (od == bd && oi < bi)) { bd = od; bi = oi; }
          }
          if (l15 == 0) {
            int row = m * 16 + lhi * 4 + r;
            dmS[wid * 32 + row] = bd; imS[wid * 32 + row] = bi;
          }
        }
      __syncthreads();
      if (t < 32) {
        float bd = dmS[t]; int bi = imS[t];
#pragma unroll
        for (int w = 1; w < 4; ++w) {
          float od = dmS[w * 32 + t]; int oi = imS[w * 32 + t];
          if (od < bd || (od == bd && oi < bi)) { bd = od; bi = oi; }
        }
        fiS[t] = bi;
        int rid = ridS[t];
        if (rid >= 0) lp += bd + zfn[rid];
      }
      __syncthreads();
      {
        const int r = t >> 3, p = t & 7;
        const int rid = ridS[r];
        if (rid >= 0) {
          const int fi = fiS[r];
          const float* qr = &fcb[((size_t)g * NK1 + fi) * DD + p * 16];
          float* orow = &out1[(size_t)rid * DD + p * 16];
#pragma unroll
          for (int q = 0; q < 4; ++q) *(float4*)&orow[q * 4] = *(const float4*)&qr[q * 4];
        }
      }
    }
  }
#pragma unroll
  for (int off = 1; off < 32; off <<= 1) lp += __shfl_xor(lp, off);
  if (t == 0) fine_partial[g * 4 + cx] = lp;
}

// ---- K4: loss reduce (one wave) -------------------------------------------
__global__ void k_final(const float* __restrict__ coarse_partial,
                        const float* __restrict__ fine_partial,
                        float* __restrict__ outL) {
  const int t = threadIdx.x;
  float s = 0.f;
#pragma unroll
  for (int i = 0; i < 4; ++i) s += coarse_partial[t + i * 64];
#pragma unroll
  for (int i = 0; i < 4; ++i) s += fine_partial[t + i * 64];
#pragma unroll
  for (int off = 1; off < 64; off <<= 1) s += __shfl_xor(s, off);
  if (t == 0) outL[0] = 1.25f * s / 1048576.0f;
}

// ---- launcher -------------------------------------------------------------
extern "C" void kernel_launch(void* const* d_in, const int* in_sizes, int n_in,
                              void* d_out, int out_size, void* d_ws, size_t ws_size,
                              hipStream_t stream) {
  const float* x     = (const float*)d_in[0];
  const float* Wc    = (const float*)d_in[1];
  const float* bc    = (const float*)d_in[2];
  const float* gc    = (const float*)d_in[3];
  const float* betac = (const float*)d_in[4];
  const float* ccb   = (const float*)d_in[5];
  const float* Wf    = (const float*)d_in[6];
  const float* bfv   = (const float*)d_in[7];
  const float* gf    = (const float*)d_in[8];
  const float* betaf = (const float*)d_in[9];
  const float* fcb   = (const float*)d_in[10];

  float* out0 = (float*)d_out;
  float* out1 = out0 + (size_t)NB * DD;
  float* outL = out0 + (size_t)2 * NB * DD;

  char* ws = (char*)d_ws;
  unsigned short* Wcomb  = (unsigned short*)(ws);
  unsigned short* Wfz    = (unsigned short*)(ws + 524288);
  unsigned short* fcbbf  = (unsigned short*)(ws + 557056);
  unsigned short* ccbbf  = (unsigned short*)(ws + 4751360);
  float*          cn_all = (float*)(ws + 4767744);
  float*          cn_c   = (float*)(ws + 4833280);
  unsigned short* zf_bf  = (unsigned short*)(ws + 4833536);
  float*          zfn    = (float*)(ws + 6930688);
  int*            ci_g   = (int*)(ws + 6963456);
  float* coarse_partial  = (float*)(ws + 6996224);
  float* fine_partial    = (float*)(ws + 6997248);

  hipFuncSetAttribute(reinterpret_cast<const void*>(kG),
                      hipFuncAttributeMaxDynamicSharedMemorySize, 73728);
  hipFuncSetAttribute(reinterpret_cast<const void*>(k3_fine),
                      hipFuncAttributeMaxDynamicSharedMemorySize, 87840);

  hipLaunchKernelGGL(k0_convert, dim3(1229), dim3(256), 0, stream,
                     Wc, Wf, fcb, ccb, Wcomb, Wfz, fcbbf, ccbbf, cn_all, cn_c);
  hipLaunchKernelGGL(kG, dim3(256), dim3(512), 73728, stream,
                     x, Wcomb, ccbbf, ccb, bc, gc, betac, cn_c,
                     bfv, gf, betaf, Wfz,
                     out0, zf_bf, zfn, ci_g, coarse_partial);
  hipLaunchKernelGGL(k3_fine, dim3(4, 64), dim3(256), 87840, stream,
                     zf_bf, fcbbf, fcb, cn_all, zfn, ci_g, out1, fine_partial);
  hipLaunchKernelGGL(k_final, dim3(1), dim3(64), 0, stream, coarse_partial, fine_partial, outL);
}

// Round 6
// 58.982 us; speedup vs baseline: 2.5072x; 1.0557x over previous
//
#include <hip/hip_runtime.h>

#define NB   8192
#define HD   1024
#define HFD  1152
#define NK0  64
#define NK1  256
#define DD   128

typedef __attribute__((ext_vector_type(4))) float  f32x4;
typedef __attribute__((ext_vector_type(8))) __bf16 bf16x8;

__device__ __forceinline__ unsigned short f2bf(float f) {
  unsigned int u = __float_as_uint(f);
  u += 0x7fffu + ((u >> 16) & 1u);
  return (unsigned short)(u >> 16);
}
__device__ __forceinline__ unsigned int pack2(float a, float b) {
  return (unsigned int)f2bf(a) | ((unsigned int)f2bf(b) << 16);
}
__device__ __forceinline__ uint4 pack8(const float4 a, const float4 b) {
  return make_uint4(pack2(a.x, a.y), pack2(a.z, a.w), pack2(b.x, b.y), pack2(b.z, b.w));
}
__device__ __forceinline__ void gload_lds16(const void* g, void* l) {
  __builtin_amdgcn_global_load_lds(
      (const __attribute__((address_space(1))) void*)g,
      (__attribute__((address_space(3))) void*)l, 16, 0, 0);
}

// ---- K0: weight/codebook conversions + norms ------------------------------
__global__ __launch_bounds__(256) void k0_convert(
    const float* __restrict__ Wc, const float* __restrict__ Wf,
    const float* __restrict__ fcb, const float* __restrict__ ccb,
    unsigned short* __restrict__ Wcomb, unsigned short* __restrict__ Wfz,
    unsigned short* __restrict__ fcbbf, unsigned short* __restrict__ ccbbf,
    float* __restrict__ cn_all, float* __restrict__ cn_c)
{
  const int bid = blockIdx.x, t = threadIdx.x;
  if (bid < 64) {
    long e0 = ((long)bid * 256 + t) * 8;
    const float4 a = *(const float4*)&Wc[e0];
    const float4 b = *(const float4*)&Wc[e0 + 4];
    *(uint4*)&Wcomb[e0] = pack8(a, b);
  } else if (bid < 136) {
    long e0 = ((long)(bid - 64) * 256 + t) * 8;
    const float4 a = *(const float4*)&Wf[e0];
    const float4 b = *(const float4*)&Wf[e0 + 4];
    const uint4 pk = pack8(a, b);
    const int row = (int)(e0 / HFD), c = (int)(e0 % HFD);
    if (c < 1024) *(uint4*)&Wcomb[(size_t)(128 + row) * HD + c] = pk;
    else          *(uint4*)&Wfz[(size_t)row * DD + (c - 1024)] = pk;
  } else if (bid < 1160) {
    long e0 = ((long)(bid - 136) * 256 + t) * 8;
    const float4 a = *(const float4*)&fcb[e0];
    const float4 b = *(const float4*)&fcb[e0 + 4];
    *(uint4*)&fcbbf[e0] = pack8(a, b);
  } else if (bid < 1164) {
    long e0 = ((long)(bid - 1160) * 256 + t) * 8;
    const float4 a = *(const float4*)&ccb[e0];
    const float4 b = *(const float4*)&ccb[e0 + 4];
    *(uint4*)&ccbbf[e0] = pack8(a, b);
  } else if (bid < 1228) {
    const int row = (bid - 1164) * 256 + t;
    const float* r = fcb + (size_t)row * DD;
    float s = 0.f;
#pragma unroll
    for (int i = 0; i < 32; ++i) {
      const float4 v = *(const float4*)&r[i * 4];
      s += v.x * v.x + v.y * v.y + v.z * v.z + v.w * v.w;
    }
    cn_all[row] = s;
  } else {
    if (t < 64) {
      const float* r = ccb + (size_t)t * DD;
      float s = 0.f;
#pragma unroll
      for (int i = 0; i < 32; ++i) {
        const float4 v = *(const float4*)&r[i * 4];
        s += v.x * v.x + v.y * v.y + v.z * v.z + v.w * v.w;
      }
      cn_c[t] = s;
    }
  }
}

// ---- KG: merged GEMM (N=256) + LN + coarse VQ + fused zf ------------------
// BM=16, BN=256, BK=64, 8 waves (512 thr), grid 512, LDS 68 KB -> 2 blocks/CU.
__global__ __launch_bounds__(512) void kG(
    const float* __restrict__ x, const unsigned short* __restrict__ Wcomb,
    const unsigned short* __restrict__ ccbbf, const float* __restrict__ ccb,
    const float* __restrict__ bc, const float* __restrict__ gc,
    const float* __restrict__ betac, const float* __restrict__ cn_c,
    const float* __restrict__ bfv, const float* __restrict__ gf,
    const float* __restrict__ betaf, const unsigned short* __restrict__ Wfz,
    float* __restrict__ out0, unsigned short* __restrict__ zf_bf,
    float* __restrict__ zfn, int* __restrict__ ci_g,
    float* __restrict__ coarse_partial)
{
  extern __shared__ char smem[];
  const int t = threadIdx.x, lane = t & 63, wid = t >> 6;
  const int l15 = lane & 15, lhi = lane >> 4;
  const int m0 = blockIdx.x * 16;

  f32x4 acc[2];
  acc[0] = (f32x4){0.f, 0.f, 0.f, 0.f};
  acc[1] = (f32x4){0.f, 0.f, 0.f, 0.f};

  const int axr = (t >> 4) & 15;    // A staging row (t<256)
  const int axc = (t & 15) << 2;    // f32 col
  float4 ra;

#define LOADA(kt) if (t < 256) ra = *(const float4*)&x[(size_t)(m0 + axr) * HD + (size_t)(kt) * 64 + axc];
#define WRITEA(bufoff)                                                          \
  if (t < 256) {                                                                \
    *(uint2*)(smem + (bufoff) + (axr << 7) + ((((t & 15) << 3)) ^ ((axr & 7) << 4))) = \
        make_uint2(pack2(ra.x, ra.y), pack2(ra.z, ra.w));                       \
  }
#define STAGEB(bufoff, kt)                                                      \
  {                                                                             \
    _Pragma("unroll")                                                           \
    for (int j = 0; j < 4; ++j) {                                               \
      const int br = (wid << 5) + (j << 3) + (lane >> 3);                       \
      const char* bsrc = (const char*)Wcomb +                                   \
          (((size_t)br * HD + (size_t)(kt) * 64) << 1) +                        \
          (((lane & 7) << 4) ^ ((br & 7) << 4));                                \
      gload_lds16(bsrc, smem + (bufoff) + 2048 + (((wid << 5) + (j << 3)) << 7)); \
    }                                                                           \
  }

  LOADA(0);
  WRITEA(0);
  STAGEB(0, 0);
  LOADA(1);
  __syncthreads();

  int cur = 0;
  for (int kt = 0; kt < 16; ++kt) {
    const int nxt = (cur ^ 1) * 34816;
    if (kt < 15) { WRITEA(nxt); STAGEB(nxt, kt + 1); }
    if (kt < 14) LOADA(kt + 2);
    const char* bufA = smem + cur * 34816;
    const char* bufB = bufA + 2048;
#pragma unroll
    for (int ks = 0; ks < 2; ++ks) {
      const int kb = (ks << 6) + (lhi << 4);
      bf16x8 a0 = *(const bf16x8*)(bufA + (l15 << 7) + (kb ^ ((l15 & 7) << 4)));
#pragma unroll
      for (int n = 0; n < 2; ++n) {
        const int rb = (wid << 5) + (n << 4) + l15;
        bf16x8 b = *(const bf16x8*)(bufB + (rb << 7) + (kb ^ ((rb & 7) << 4)));
        acc[n] = __builtin_amdgcn_mfma_f32_16x16x32_bf16(a0, b, acc[n], 0, 0, 0);
      }
    }
    __syncthreads();
    cur ^= 1;
  }
#undef LOADA
#undef WRITEA
#undef STAGEB

  // ---- epilogue LDS overlay ----
  int*   cxS = (int*)  smem;                              // [16]
  unsigned short* zqb = (unsigned short*)(smem + 128);    // [16][136]
  float* zcf          = (float*)(smem + 4608);            // [16][132] (E1-E2)
  float* zff          = (float*)(smem + 13056);           // [16][132] (E1-E7)
  unsigned short* cbb = (unsigned short*)(smem + 21504);  // [64][136] (E1-E3)
  unsigned short* Wz  = (unsigned short*)(smem + 21504);  // [128][136](E5-E6)
  unsigned short* zbb = (unsigned short*)(smem + 56320);  // [16][136] (E2-E3)
  float* zn  = (float*)(smem + 60672);                    // [16]
  float* cnS = (float*)(smem + 60736);                    // [64]
  float* dmS = (float*)(smem + 60992);                    // [4][16]
  int*   imS = (int*)  (smem + 61248);                    // [4][16]

  // E1: distribute acc; stage coarse codebook
  if (wid < 4) {
#pragma unroll
    for (int n = 0; n < 2; ++n)
#pragma unroll
      for (int r = 0; r < 4; ++r) {
        int col = (wid << 5) + (n << 4) + l15;
        zcf[((lhi << 2) + r) * 132 + col] = acc[n][r] + bc[col];
      }
  } else {
#pragma unroll
    for (int n = 0; n < 2; ++n)
#pragma unroll
      for (int r = 0; r < 4; ++r) {
        int col = ((wid - 4) << 5) + (n << 4) + l15;
        zff[((lhi << 2) + r) * 132 + col] = acc[n][r] + bfv[col];
      }
  }
#pragma unroll
  for (int i = 0; i < 2; ++i) {
    int idx = t + i * 512;
    int row = idx >> 4, c8 = (idx & 15) << 3;
    *(uint4*)&cbb[row * 136 + c8] = *(const uint4*)&ccbbf[(row << 7) + c8];
  }
  if (t < 64) cnS[t] = cn_c[t];
  __syncthreads();

  // E2: LayerNorm(z_c), 32 thr/row; ||z||^2; z -> bf16
  {
    const int r = t >> 5, p = t & 31;
    const float4 u = *(const float4*)&zcf[r * 132 + (p << 2)];
    float v[4] = {u.x, u.y, u.z, u.w};
    float s = v[0] + v[1] + v[2] + v[3];
    float s2 = v[0]*v[0] + v[1]*v[1] + v[2]*v[2] + v[3]*v[3];
#pragma unroll
    for (int off = 1; off < 32; off <<= 1) { s += __shfl_xor(s, off); s2 += __shfl_xor(s2, off); }
    const float mu   = s * (1.f / 128.f);
    const float rstd = rsqrtf(s2 * (1.f / 128.f) - mu * mu + 1e-5f);
    float s2n = 0.f;
#pragma unroll
    for (int j = 0; j < 4; ++j) {
      int col = (p << 2) + j;
      float vv = (v[j] - mu) * rstd * gc[col] + betac[col];
      v[j] = vv; s2n += vv * vv;
    }
#pragma unroll
    for (int off = 1; off < 32; off <<= 1) s2n += __shfl_xor(s2n, off);
    if (p == 0) zn[r] = s2n;
    *(uint2*)&zbb[r * 136 + (p << 2)] = make_uint2(pack2(v[0], v[1]), pack2(v[2], v[3]));
  }
  __syncthreads();

  // E3: coarse distances via MFMA (waves 0-3; 16 codes x 16 rows each)
  if (wid < 4) {
    f32x4 dacc = (f32x4){0.f, 0.f, 0.f, 0.f};
#pragma unroll
    for (int ks = 0; ks < 4; ++ks) {
      const int lk = (ks << 5) + (lhi << 3);
      bf16x8 a = *(const bf16x8*)&cbb[((wid << 4) + l15) * 136 + lk];
      bf16x8 b = *(const bf16x8*)&zbb[l15 * 136 + lk];
      dacc = __builtin_amdgcn_mfma_f32_16x16x32_bf16(a, b, dacc, 0, 0, 0);
    }
    float bd = 3.4e38f; int bi = 0;
#pragma unroll
    for (int r = 0; r < 4; ++r) {
      int code = (wid << 4) + (lhi << 2) + r;
      float d = cnS[code] - 2.f * dacc[r];
      if (d < bd || (d == bd && code < bi)) { bd = d; bi = code; }
    }
#pragma unroll
    for (int off = 16; off < 64; off <<= 1) {
      float od = __shfl_xor(bd, off); int oi = __shfl_xor(bi, off);
      if (od < bd || (od == bd && oi < bi)) { bd = od; bi = oi; }
    }
    if (lhi == 0) { dmS[wid * 16 + l15] = bd; imS[wid * 16 + l15] = bi; }
  }
  __syncthreads();

  // E4: final coarse argmin + loss partial + ci
  if (t < 16) {
    float bd = dmS[t]; int bi = imS[t];
#pragma unroll
    for (int w = 1; w < 4; ++w) {
      float od = dmS[w * 16 + t]; int oi = imS[w * 16 + t];
      if (od < bd || (od == bd && oi < bi)) { bd = od; bi = oi; }
    }
    ci_g[m0 + t] = bi;
    cxS[t] = bi;
    float lp = bd + zn[t];
#pragma unroll
    for (int off = 1; off < 16; off <<= 1) lp += __shfl_xor(lp, off);
    if (t == 0) coarse_partial[blockIdx.x] = lp;
  }
  __syncthreads();

  // E5: stage Wfz + zcq(bf16); write out0
  {
#pragma unroll
    for (int i = 0; i < 4; ++i) {
      int idx = t + i * 512;
      int row = idx >> 4, c8 = (idx & 15) << 3;
      *(uint4*)&Wz[row * 136 + c8] = *(const uint4*)&Wfz[(row << 7) + c8];
    }
    if (t < 256) {
      const int r = t >> 4, p = t & 15;
      const int c = cxS[r];
      *(uint4*)&zqb[r * 136 + (p << 3)] = *(const uint4*)&ccbbf[(c << 7) + (p << 3)];
      const float4 q0 = *(const float4*)&ccb[(c << 7) + (p << 3)];
      const float4 q1 = *(const float4*)&ccb[(c << 7) + (p << 3) + 4];
      *(float4*)&out0[(size_t)(m0 + r) * DD + (p << 3)]     = q0;
      *(float4*)&out0[(size_t)(m0 + r) * DD + (p << 3) + 4] = q1;
    }
  }
  __syncthreads();

  // E6: zff += zcq @ Wfz^T (wave wid -> cols wid*16..+15)
  {
    f32x4 a2 = (f32x4){0.f, 0.f, 0.f, 0.f};
#pragma unroll
    for (int ks = 0; ks < 4; ++ks) {
      const int lk = (ks << 5) + (lhi << 3);
      bf16x8 a0 = *(const bf16x8*)&zqb[l15 * 136 + lk];
      bf16x8 b  = *(const bf16x8*)&Wz[((wid << 4) + l15) * 136 + lk];
      a2 = __builtin_amdgcn_mfma_f32_16x16x32_bf16(a0, b, a2, 0, 0, 0);
    }
#pragma unroll
    for (int r = 0; r < 4; ++r)
      zff[((lhi << 2) + r) * 132 + (wid << 4) + l15] += a2[r];
  }
  __syncthreads();

  // E7: LayerNorm(z_f) -> zf_bf + zfn
  {
    const int r = t >> 5, p = t & 31;
    const float4 u = *(const float4*)&zff[r * 132 + (p << 2)];
    float v[4] = {u.x, u.y, u.z, u.w};
    float s = v[0] + v[1] + v[2] + v[3];
    float s2 = v[0]*v[0] + v[1]*v[1] + v[2]*v[2] + v[3]*v[3];
#pragma unroll
    for (int off = 1; off < 32; off <<= 1) { s += __shfl_xor(s, off); s2 += __shfl_xor(s2, off); }
    const float mu   = s * (1.f / 128.f);
    const float rstd = rsqrtf(s2 * (1.f / 128.f) - mu * mu + 1e-5f);
    float s2n = 0.f;
    float w0, w1, w2, w3;
    {
      int col = (p << 2);
      w0 = (v[0] - mu) * rstd * gf[col]     + betaf[col];
      w1 = (v[1] - mu) * rstd * gf[col + 1] + betaf[col + 1];
      w2 = (v[2] - mu) * rstd * gf[col + 2] + betaf[col + 2];
      w3 = (v[3] - mu) * rstd * gf[col + 3] + betaf[col + 3];
      s2n = w0*w0 + w1*w1 + w2*w2 + w3*w3;
    }
#pragma unroll
    for (int off = 1; off < 32; off <<= 1) s2n += __shfl_xor(s2n, off);
    if (p == 0) zfn[m0 + r] = s2n;
    *(uint2*)&zf_bf[(size_t)(m0 + r) * DD + (p << 2)] = make_uint2(pack2(w0, w1), pack2(w2, w3));
  }
}

// ---- K3: fine VQ; blocks self-select rows by scanning ci_g ----------------
__global__ __launch_bounds__(256) void k3_fine(
    const unsigned short* __restrict__ zf_bf, const unsigned short* __restrict__ fcbbf,
    const float* __restrict__ fcb, const float* __restrict__ cn_all,
    const float* __restrict__ zfn, const int* __restrict__ ci_g,
    float* __restrict__ out1, float* __restrict__ fine_partial)
{
  extern __shared__ char smem[];
  unsigned short* Vb  = (unsigned short*)smem;            // [256][136]
  unsigned short* zfL = (unsigned short*)(smem + 69632);  // [32][136]
  int*   list = (int*)  (smem + 78336);                   // [2048]
  int*   ridS = (int*)  (smem + 86528);                   // [32]
  float* dmS  = (float*)(smem + 86656);                   // [4][32]
  int*   imS  = (int*)  (smem + 87168);                   // [4][32]
  int*   fiS  = (int*)  (smem + 87680);                   // [32]
  int*   wsum = (int*)  (smem + 87808);                   // [8]

  const int g = blockIdx.y, cx = blockIdx.x;   // cx in [0,4)
  const int t = threadIdx.x, lane = t & 63, wid = t >> 6;
  const int l15 = lane & 15, lhi = lane >> 4;

  // stage full group codebook FIRST (HBM latency hides under the scan below)
#pragma unroll
  for (int i = 0; i < 16; ++i) {
    int idx = t + i * 256; int row = idx >> 4, c8 = (idx & 15) * 8;
    *(uint4*)&Vb[row * 136 + c8] = *(const uint4*)&fcbbf[((size_t)g * NK1 + row) * DD + c8];
  }
  float cnr[4];
#pragma unroll
  for (int n = 0; n < 4; ++n) cnr[n] = cn_all[g * NK1 + wid * 64 + n * 16 + l15];

  // deterministic compaction of {i : ci_g[i]==g}
  const int seg = t * 32;
  int mcount = 0;
#pragma unroll 8
  for (int q = 0; q < 32; ++q) mcount += (ci_g[seg + q] == g);
  int v = mcount;
#pragma unroll
  for (int off = 1; off < 64; off <<= 1) {
    int o = __shfl_up(v, off);
    if (lane >= off) v += o;
  }
  if (lane == 63) wsum[wid] = v;
  __syncthreads();
  if (t == 0) {
    int run = 0;
#pragma unroll
    for (int w = 0; w < 4; ++w) { int c = wsum[w]; wsum[w] = run; run += c; }
    wsum[4] = run;
  }
  __syncthreads();
  const int total = wsum[4];
  const int tcap = total > 2048 ? 2048 : total;
  {
    int j = wsum[wid] + v - mcount;
    for (int q = 0; q < 32; ++q) {
      if (ci_g[seg + q] == g) { if (j < 2048) list[j] = seg + q; ++j; }
    }
  }
  __syncthreads();

  float lp = 0.f;
  for (int r0 = cx * 32; r0 < tcap; r0 += 128) {
    __syncthreads();
    if (t < 32) ridS[t] = (r0 + t < tcap) ? list[r0 + t] : -1;
    __syncthreads();
#pragma unroll
    for (int i = 0; i < 2; ++i) {
      int idx = t + i * 256; int row = idx >> 4, c8 = (idx & 15) * 8;
      int rid = ridS[row];
      uint4 vv = make_uint4(0u, 0u, 0u, 0u);
      if (rid >= 0) vv = *(const uint4*)&zf_bf[(size_t)rid * DD + c8];
      *(uint4*)&zfL[row * 136 + c8] = vv;
    }
    __syncthreads();
    f32x4 acc[2][4];
#pragma unroll
    for (int m = 0; m < 2; ++m)
#pragma unroll
      for (int n = 0; n < 4; ++n) acc[m][n] = (f32x4){0.f, 0.f, 0.f, 0.f};
#pragma unroll
    for (int ks = 0; ks < 4; ++ks) {
      const int lk = ks * 32 + lhi * 8;
      bf16x8 a0 = *(const bf16x8*)&zfL[l15 * 136 + lk];
      bf16x8 a1 = *(const bf16x8*)&zfL[(16 + l15) * 136 + lk];
#pragma unroll
      for (int n = 0; n < 4; ++n) {
        bf16x8 b = *(const bf16x8*)&Vb[(wid * 64 + n * 16 + l15) * 136 + lk];
        acc[0][n] = __builtin_amdgcn_mfma_f32_16x16x32_bf16(a0, b, acc[0][n], 0, 0, 0);
        acc[1][n] = __builtin_amdgcn_mfma_f32_16x16x32_bf16(a1, b, acc[1][n], 0, 0, 0);
      }
    }
#pragma unroll
    for (int m = 0; m < 2; ++m)
#pragma unroll
      for (int r = 0; r < 4; ++r) {
        float bd = 3.4e38f; int bi = 0;
#pragma unroll
        for (int n = 0; n < 4; ++n) {
          int code = wid * 64 + n * 16 + l15;
          float d = cnr[n] - 2.f * acc[m][n][r];
          if (d < bd || (d == bd && code < bi)) { bd = d; bi = code; }
        }
#pragma unroll
        for (int off = 1; off < 16; off <<= 1) {
          float od = __shfl_xor(bd, off); int oi = __shfl_xor(bi, off);
          if (od < bd || (od == bd && oi < bi)) { bd = od; bi = oi; }
        }
        if (l15 == 0) {
          int row = m * 16 + lhi * 4 + r;
          dmS[wid * 32 + row] = bd; imS[wid * 32 + row] = bi;
        }
      }
    __syncthreads();
    if (t < 32) {
      float bd = dmS[t]; int bi = imS[t];
#pragma unroll
      for (int w = 1; w < 4; ++w) {
        float od = dmS[w * 32 + t]; int oi = imS[w * 32 + t];
        if (od < bd || (od == bd && oi < bi)) { bd = od; bi = oi; }
      }
      fiS[t] = bi;
      int rid = ridS[t];
      if (rid >= 0) lp += bd + zfn[rid];
    }
    __syncthreads();
    {
      const int r = t >> 3, p = t & 7;
      const int rid = ridS[r];
      if (rid >= 0) {
        const int fi = fiS[r];
        const float* qr = &fcb[((size_t)g * NK1 + fi) * DD + p * 16];
        float* orow = &out1[(size_t)rid * DD + p * 16];
#pragma unroll
        for (int q = 0; q < 4; ++q) *(float4*)&orow[q * 4] = *(const float4*)&qr[q * 4];
      }
    }
  }
#pragma unroll
  for (int off = 1; off < 32; off <<= 1) lp += __shfl_xor(lp, off);
  if (t == 0) fine_partial[g * 4 + cx] = lp;
}

// ---- K4: loss reduce (one wave) -------------------------------------------
__global__ void k_final(const float* __restrict__ coarse_partial,
                        const float* __restrict__ fine_partial,
                        float* __restrict__ outL) {
  const int t = threadIdx.x;
  float s = 0.f;
#pragma unroll
  for (int i = 0; i < 8; ++i) s += coarse_partial[t + i * 64];
#pragma unroll
  for (int i = 0; i < 4; ++i) s += fine_partial[t + i * 64];
#pragma unroll
  for (int off = 1; off < 64; off <<= 1) s += __shfl_xor(s, off);
  if (t == 0) outL[0] = 1.25f * s / 1048576.0f;
}

// ---- launcher -------------------------------------------------------------
extern "C" void kernel_launch(void* const* d_in, const int* in_sizes, int n_in,
                              void* d_out, int out_size, void* d_ws, size_t ws_size,
                              hipStream_t stream) {
  const float* x     = (const float*)d_in[0];
  const float* Wc    = (const float*)d_in[1];
  const float* bc    = (const float*)d_in[2];
  const float* gc    = (const float*)d_in[3];
  const float* betac = (const float*)d_in[4];
  const float* ccb   = (const float*)d_in[5];
  const float* Wf    = (const float*)d_in[6];
  const float* bfv   = (const float*)d_in[7];
  const float* gf    = (const float*)d_in[8];
  const float* betaf = (const float*)d_in[9];
  const float* fcb   = (const float*)d_in[10];

  float* out0 = (float*)d_out;
  float* out1 = out0 + (size_t)NB * DD;
  float* outL = out0 + (size_t)2 * NB * DD;

  char* ws = (char*)d_ws;
  unsigned short* Wcomb  = (unsigned short*)(ws);
  unsigned short* Wfz    = (unsigned short*)(ws + 524288);
  unsigned short* fcbbf  = (unsigned short*)(ws + 557056);
  unsigned short* ccbbf  = (unsigned short*)(ws + 4751360);
  float*          cn_all = (float*)(ws + 4767744);
  float*          cn_c   = (float*)(ws + 4833280);
  unsigned short* zf_bf  = (unsigned short*)(ws + 4833536);
  float*          zfn    = (float*)(ws + 6930688);
  int*            ci_g   = (int*)(ws + 6963456);
  float* coarse_partial  = (float*)(ws + 6996224);
  float* fine_partial    = (float*)(ws + 6998272);

  hipFuncSetAttribute(reinterpret_cast<const void*>(kG),
                      hipFuncAttributeMaxDynamicSharedMemorySize, 69632);
  hipFuncSetAttribute(reinterpret_cast<const void*>(k3_fine),
                      hipFuncAttributeMaxDynamicSharedMemorySize, 87840);

  hipLaunchKernelGGL(k0_convert, dim3(1229), dim3(256), 0, stream,
                     Wc, Wf, fcb, ccb, Wcomb, Wfz, fcbbf, ccbbf, cn_all, cn_c);
  hipLaunchKernelGGL(kG, dim3(512), dim3(512), 69632, stream,
                     x, Wcomb, ccbbf, ccb, bc, gc, betac, cn_c,
                     bfv, gf, betaf, Wfz,
                     out0, zf_bf, zfn, ci_g, coarse_partial);
  hipLaunchKernelGGL(k3_fine, dim3(4, 64), dim3(256), 87840, stream,
                     zf_bf, fcbbf, fcb, cn_all, zfn, ci_g, out1, fine_partial);
  hipLaunchKernelGGL(k_final, dim3(1), dim3(64), 0, stream, coarse_partial, fine_partial, outL);
}

// Round 7
// 57.262 us; speedup vs baseline: 2.5826x; 1.0300x over previous
//
#include <hip/hip_runtime.h>

#define NB   8192
#define HD   1024
#define HFD  1152
#define NK0  64
#define NK1  256
#define DD   128

typedef __attribute__((ext_vector_type(4))) float  f32x4;
typedef __attribute__((ext_vector_type(8))) __bf16 bf16x8;

__device__ __forceinline__ unsigned short f2bf(float f) {
  unsigned int u = __float_as_uint(f);
  u += 0x7fffu + ((u >> 16) & 1u);
  return (unsigned short)(u >> 16);
}
__device__ __forceinline__ unsigned int pack2(float a, float b) {
  return (unsigned int)f2bf(a) | ((unsigned int)f2bf(b) << 16);
}
__device__ __forceinline__ uint4 pack8(const float4 a, const float4 b) {
  return make_uint4(pack2(a.x, a.y), pack2(a.z, a.w), pack2(b.x, b.y), pack2(b.z, b.w));
}
__device__ __forceinline__ void gload_lds16(const void* g, void* l) {
  __builtin_amdgcn_global_load_lds(
      (const __attribute__((address_space(1))) void*)g,
      (__attribute__((address_space(3))) void*)l, 16, 0, 0);
}

// ---- K0: weight/codebook conversions + norms ------------------------------
__global__ __launch_bounds__(256) void k0_convert(
    const float* __restrict__ Wc, const float* __restrict__ Wf,
    const float* __restrict__ fcb, const float* __restrict__ ccb,
    unsigned short* __restrict__ Wcomb, unsigned short* __restrict__ Wfz,
    unsigned short* __restrict__ fcbbf, unsigned short* __restrict__ ccbbf,
    float* __restrict__ cn_all, float* __restrict__ cn_c)
{
  const int bid = blockIdx.x, t = threadIdx.x;
  if (bid < 64) {
    long e0 = ((long)bid * 256 + t) * 8;
    const float4 a = *(const float4*)&Wc[e0];
    const float4 b = *(const float4*)&Wc[e0 + 4];
    *(uint4*)&Wcomb[e0] = pack8(a, b);
  } else if (bid < 136) {
    long e0 = ((long)(bid - 64) * 256 + t) * 8;
    const float4 a = *(const float4*)&Wf[e0];
    const float4 b = *(const float4*)&Wf[e0 + 4];
    const uint4 pk = pack8(a, b);
    const int row = (int)(e0 / HFD), c = (int)(e0 % HFD);
    if (c < 1024) *(uint4*)&Wcomb[(size_t)(128 + row) * HD + c] = pk;
    else          *(uint4*)&Wfz[(size_t)row * DD + (c - 1024)] = pk;
  } else if (bid < 1160) {
    long e0 = ((long)(bid - 136) * 256 + t) * 8;
    const float4 a = *(const float4*)&fcb[e0];
    const float4 b = *(const float4*)&fcb[e0 + 4];
    *(uint4*)&fcbbf[e0] = pack8(a, b);
  } else if (bid < 1164) {
    long e0 = ((long)(bid - 1160) * 256 + t) * 8;
    const float4 a = *(const float4*)&ccb[e0];
    const float4 b = *(const float4*)&ccb[e0 + 4];
    *(uint4*)&ccbbf[e0] = pack8(a, b);
  } else if (bid < 1228) {
    const int row = (bid - 1164) * 256 + t;
    const float* r = fcb + (size_t)row * DD;
    float s = 0.f;
#pragma unroll
    for (int i = 0; i < 32; ++i) {
      const float4 v = *(const float4*)&r[i * 4];
      s += v.x * v.x + v.y * v.y + v.z * v.z + v.w * v.w;
    }
    cn_all[row] = s;
  } else {
    if (t < 64) {
      const float* r = ccb + (size_t)t * DD;
      float s = 0.f;
#pragma unroll
      for (int i = 0; i < 32; ++i) {
        const float4 v = *(const float4*)&r[i * 4];
        s += v.x * v.x + v.y * v.y + v.z * v.z + v.w * v.w;
      }
      cn_c[t] = s;
    }
  }
}

// ---- KG: merged GEMM (N=256) + LN + coarse VQ + fused zf ------------------
// BM=32, BN=256, BK=64, 8 waves (512 thr), grid 256.
// Triple-buffered LDS (3 x 36864B), counted vmcnt(10) pipeline, raw barriers.
__global__ __launch_bounds__(512) void kG(
    const float* __restrict__ x, const unsigned short* __restrict__ Wcomb,
    const unsigned short* __restrict__ ccbbf, const float* __restrict__ ccb,
    const float* __restrict__ bc, const float* __restrict__ gc,
    const float* __restrict__ betac, const float* __restrict__ cn_c,
    const float* __restrict__ bfv, const float* __restrict__ gf,
    const float* __restrict__ betaf, const unsigned short* __restrict__ Wfz,
    float* __restrict__ out0, unsigned short* __restrict__ zf_bf,
    float* __restrict__ zfn, int* __restrict__ ci_g,
    float* __restrict__ coarse_partial)
{
  extern __shared__ char smem[];
  const int t = threadIdx.x, lane = t & 63, wid = t >> 6;
  const int l15 = lane & 15, lhi = lane >> 4;
  const int m0 = blockIdx.x * 32;

  f32x4 acc[2][2];
#pragma unroll
  for (int m = 0; m < 2; ++m)
#pragma unroll
    for (int n = 0; n < 2; ++n) acc[m][n] = (f32x4){0.f, 0.f, 0.f, 0.f};

  const int axr = t >> 4;           // A staging row 0..31 (all 512 threads)
  const int axc = (t & 15) << 2;    // f32 col
  float4 ra[4];                     // 4-deep A prefetch

#define LOADA(tile, slot) \
  ra[slot] = *(const float4*)&x[(size_t)(m0 + axr) * HD + (size_t)(tile) * 64 + axc];
#define WRITEA(bufoff, slot)                                                    \
  *(uint2*)(smem + (bufoff) + (axr << 7) + ((((t & 15) << 3)) ^ ((axr & 7) << 4))) = \
      make_uint2(pack2(ra[slot].x, ra[slot].y), pack2(ra[slot].z, ra[slot].w));
#define STAGEB(bufoff, kt)                                                      \
  {                                                                             \
    _Pragma("unroll")                                                           \
    for (int j = 0; j < 4; ++j) {                                               \
      const int br = (wid << 5) + (j << 3) + (lane >> 3);                       \
      const char* bsrc = (const char*)Wcomb +                                   \
          (((size_t)br * HD + (size_t)(kt) * 64) << 1) +                        \
          (((lane & 7) << 4) ^ ((br & 7) << 4));                                \
      gload_lds16(bsrc, smem + (bufoff) + 4096 + (((wid << 5) + (j << 3)) << 7)); \
    }                                                                           \
  }

  LOADA(0, 0); LOADA(1, 1); LOADA(2, 2); LOADA(3, 3);

  // pipeline: at iter kt, stage tile kt+2 into buf (kt+2)%3, compute tile kt
  // from buf kt%3. Per-wave VMEM issue = 5/iter (uniform, clamped tail) so
  // vmcnt(10) == "everything older than 2 iterations is complete".
  for (int kt = -2; kt < 16; ++kt) {
    const int st = kt + 2;
    const int stc = st > 15 ? 15 : st;            // clamped staged tile
    const int sbuf = (st % 3) * 36864;
    const int slot = st & 3;
    WRITEA(sbuf, slot);
    STAGEB(sbuf, stc);
    {
      const int lt = (kt + 6 > 15) ? 15 : (kt + 6);
      LOADA(lt, slot);                            // (kt+6)&3 == slot
    }
    if (kt >= 0) {
      asm volatile("s_waitcnt vmcnt(10) lgkmcnt(0)" ::: "memory");
      __builtin_amdgcn_s_barrier();
      __builtin_amdgcn_sched_barrier(0);
      const char* bufA = smem + (kt % 3) * 36864;
      const char* bufB = bufA + 4096;
#pragma unroll
      for (int ks = 0; ks < 2; ++ks) {
        const int kb = (ks << 6) + (lhi << 4);
        const int sa = kb ^ ((l15 & 7) << 4);
        bf16x8 a0 = *(const bf16x8*)(bufA + (l15 << 7) + sa);
        bf16x8 a1 = *(const bf16x8*)(bufA + ((l15 + 16) << 7) + sa);
#pragma unroll
        for (int n = 0; n < 2; ++n) {
          const int rb = (wid << 5) + (n << 4) + l15;
          bf16x8 b = *(const bf16x8*)(bufB + (rb << 7) + (kb ^ ((rb & 7) << 4)));
          acc[0][n] = __builtin_amdgcn_mfma_f32_16x16x32_bf16(a0, b, acc[0][n], 0, 0, 0);
          acc[1][n] = __builtin_amdgcn_mfma_f32_16x16x32_bf16(a1, b, acc[1][n], 0, 0, 0);
        }
      }
      asm volatile("" ::: "memory");
      __builtin_amdgcn_s_barrier();
    }
  }
#undef LOADA
#undef WRITEA
#undef STAGEB

  __syncthreads();   // drains outstanding (dummy) gload_lds before LDS overlay

  // ---- epilogue LDS overlay ----
  int*   cxS = (int*)  smem;                              // [32]      (E4-)
  unsigned short* zqb = (unsigned short*)(smem + 128);    // [32][136] (E5-)
  float* zcf          = (float*)(smem + 9216);            // [32][132] (E1-E2)
  float* zff          = (float*)(smem + 26112);           // [32][132] (E1-E7)
  unsigned short* cbb = (unsigned short*)(smem + 43008);  // [64][136] (E1-E3)
  unsigned short* Wz  = (unsigned short*)(smem + 43008);  // [128][136](E5-E6)
  unsigned short* zbb = (unsigned short*)(smem + 78336);  // [32][136] (E2-E3)
  float* zn  = (float*)(smem + 87040);                    // [32]
  float* cnS = (float*)(smem + 87168);                    // [64]
  float* dmS = (float*)(smem + 87424);                    // [4][32]
  int*   imS = (int*)  (smem + 87936);                    // [4][32]

  // E1: distribute acc; stage coarse codebook
  if (wid < 4) {
#pragma unroll
    for (int m = 0; m < 2; ++m)
#pragma unroll
      for (int n = 0; n < 2; ++n)
#pragma unroll
        for (int r = 0; r < 4; ++r) {
          int row = (m << 4) + (lhi << 2) + r;
          int col = (wid << 5) + (n << 4) + l15;
          zcf[row * 132 + col] = acc[m][n][r] + bc[col];
        }
  } else {
#pragma unroll
    for (int m = 0; m < 2; ++m)
#pragma unroll
      for (int n = 0; n < 2; ++n)
#pragma unroll
        for (int r = 0; r < 4; ++r) {
          int row = (m << 4) + (lhi << 2) + r;
          int col = ((wid - 4) << 5) + (n << 4) + l15;
          zff[row * 132 + col] = acc[m][n][r] + bfv[col];
        }
  }
#pragma unroll
  for (int i = 0; i < 2; ++i) {
    int idx = t + i * 512;
    int row = idx >> 4, c8 = (idx & 15) << 3;
    *(uint4*)&cbb[row * 136 + c8] = *(const uint4*)&ccbbf[(row << 7) + c8];
  }
  if (t < 64) cnS[t] = cn_c[t];
  __syncthreads();

  // E2: LayerNorm(z_c); ||z||^2; z -> bf16
  {
    const int r = t >> 4, p = t & 15;
    float v[8];
    const float4 u0 = *(const float4*)&zcf[r * 132 + (p << 3)];
    const float4 u1 = *(const float4*)&zcf[r * 132 + (p << 3) + 4];
    v[0]=u0.x; v[1]=u0.y; v[2]=u0.z; v[3]=u0.w; v[4]=u1.x; v[5]=u1.y; v[6]=u1.z; v[7]=u1.w;
    float s = 0.f, s2 = 0.f;
#pragma unroll
    for (int j = 0; j < 8; ++j) { s += v[j]; s2 += v[j] * v[j]; }
#pragma unroll
    for (int off = 1; off < 16; off <<= 1) { s += __shfl_xor(s, off); s2 += __shfl_xor(s2, off); }
    const float mu   = s * (1.f / 128.f);
    const float rstd = rsqrtf(s2 * (1.f / 128.f) - mu * mu + 1e-5f);
    float s2n = 0.f;
#pragma unroll
    for (int j = 0; j < 8; ++j) {
      int col = (p << 3) + j;
      float vv = (v[j] - mu) * rstd * gc[col] + betac[col];
      v[j] = vv; s2n += vv * vv;
    }
#pragma unroll
    for (int off = 1; off < 16; off <<= 1) s2n += __shfl_xor(s2n, off);
    if (p == 0) zn[r] = s2n;
    *(uint4*)&zbb[r * 136 + (p << 3)] =
        make_uint4(pack2(v[0], v[1]), pack2(v[2], v[3]), pack2(v[4], v[5]), pack2(v[6], v[7]));
  }
  __syncthreads();

  // E3: coarse distances via MFMA (cg = code grp, zg = z-row grp)
  {
    const int cg = wid & 3, zg = wid >> 2;
    f32x4 dacc = (f32x4){0.f, 0.f, 0.f, 0.f};
#pragma unroll
    for (int ks = 0; ks < 4; ++ks) {
      const int lk = (ks << 5) + (lhi << 3);
      bf16x8 a = *(const bf16x8*)&cbb[((cg << 4) + l15) * 136 + lk];
      bf16x8 b = *(const bf16x8*)&zbb[((zg << 4) + l15) * 136 + lk];
      dacc = __builtin_amdgcn_mfma_f32_16x16x32_bf16(a, b, dacc, 0, 0, 0);
    }
    float bd = 3.4e38f; int bi = 0;
#pragma unroll
    for (int r = 0; r < 4; ++r) {
      int code = (cg << 4) + (lhi << 2) + r;
      float d = cnS[code] - 2.f * dacc[r];
      if (d < bd || (d == bd && code < bi)) { bd = d; bi = code; }
    }
#pragma unroll
    for (int off = 16; off < 64; off <<= 1) {
      float od = __shfl_xor(bd, off); int oi = __shfl_xor(bi, off);
      if (od < bd || (od == bd && oi < bi)) { bd = od; bi = oi; }
    }
    if (lhi == 0) { dmS[cg * 32 + (zg << 4) + l15] = bd; imS[cg * 32 + (zg << 4) + l15] = bi; }
  }
  __syncthreads();

  // E4: final coarse argmin + loss partial + ci
  if (t < 32) {
    float bd = dmS[t]; int bi = imS[t];
#pragma unroll
    for (int w = 1; w < 4; ++w) {
      float od = dmS[w * 32 + t]; int oi = imS[w * 32 + t];
      if (od < bd || (od == bd && oi < bi)) { bd = od; bi = oi; }
    }
    ci_g[m0 + t] = bi;
    cxS[t] = bi;
    float lp = bd + zn[t];
#pragma unroll
    for (int off = 1; off < 32; off <<= 1) lp += __shfl_xor(lp, off);
    if (t == 0) coarse_partial[blockIdx.x] = lp;
  }
  __syncthreads();

  // E5: stage Wfz + zcq(bf16); write out0
  {
#pragma unroll
    for (int i = 0; i < 4; ++i) {
      int idx = t + i * 512;
      int row = idx >> 4, c8 = (idx & 15) << 3;
      *(uint4*)&Wz[row * 136 + c8] = *(const uint4*)&Wfz[(row << 7) + c8];
    }
    if (t < 512) {
      const int r = t >> 4, p = t & 15;
      const int c = cxS[r];
      *(uint4*)&zqb[r * 136 + (p << 3)] = *(const uint4*)&ccbbf[(c << 7) + (p << 3)];
      const float4 q0 = *(const float4*)&ccb[(c << 7) + (p << 3)];
      const float4 q1 = *(const float4*)&ccb[(c << 7) + (p << 3) + 4];
      *(float4*)&out0[(size_t)(m0 + r) * DD + (p << 3)]     = q0;
      *(float4*)&out0[(size_t)(m0 + r) * DD + (p << 3) + 4] = q1;
    }
  }
  __syncthreads();

  // E6: zff += zcq @ Wfz^T (wave wid -> cols wid*16..+15)
  {
    f32x4 a2[2];
    a2[0] = (f32x4){0.f, 0.f, 0.f, 0.f};
    a2[1] = (f32x4){0.f, 0.f, 0.f, 0.f};
#pragma unroll
    for (int ks = 0; ks < 4; ++ks) {
      const int lk = (ks << 5) + (lhi << 3);
      bf16x8 a0 = *(const bf16x8*)&zqb[l15 * 136 + lk];
      bf16x8 a1 = *(const bf16x8*)&zqb[(16 + l15) * 136 + lk];
      bf16x8 b  = *(const bf16x8*)&Wz[((wid << 4) + l15) * 136 + lk];
      a2[0] = __builtin_amdgcn_mfma_f32_16x16x32_bf16(a0, b, a2[0], 0, 0, 0);
      a2[1] = __builtin_amdgcn_mfma_f32_16x16x32_bf16(a1, b, a2[1], 0, 0, 0);
    }
#pragma unroll
    for (int m = 0; m < 2; ++m)
#pragma unroll
      for (int r = 0; r < 4; ++r)
        zff[((m << 4) + (lhi << 2) + r) * 132 + (wid << 4) + l15] += a2[m][r];
  }
  __syncthreads();

  // E7: LayerNorm(z_f) -> zf_bf + zfn
  {
    const int r = t >> 4, p = t & 15;
    float v[8];
    const float4 u0 = *(const float4*)&zff[r * 132 + (p << 3)];
    const float4 u1 = *(const float4*)&zff[r * 132 + (p << 3) + 4];
    v[0]=u0.x; v[1]=u0.y; v[2]=u0.z; v[3]=u0.w; v[4]=u1.x; v[5]=u1.y; v[6]=u1.z; v[7]=u1.w;
    float s = 0.f, s2 = 0.f;
#pragma unroll
    for (int j = 0; j < 8; ++j) { s += v[j]; s2 += v[j] * v[j]; }
#pragma unroll
    for (int off = 1; off < 16; off <<= 1) { s += __shfl_xor(s, off); s2 += __shfl_xor(s2, off); }
    const float mu   = s * (1.f / 128.f);
    const float rstd = rsqrtf(s2 * (1.f / 128.f) - mu * mu + 1e-5f);
    float s2n = 0.f;
    unsigned int o[4];
#pragma unroll
    for (int jj = 0; jj < 4; ++jj) {
      int col = (p << 3) + 2 * jj;
      float v0 = (v[2 * jj]     - mu) * rstd * gf[col]     + betaf[col];
      float v1 = (v[2 * jj + 1] - mu) * rstd * gf[col + 1] + betaf[col + 1];
      s2n += v0 * v0 + v1 * v1;
      o[jj] = pack2(v0, v1);
    }
#pragma unroll
    for (int off = 1; off < 16; off <<= 1) s2n += __shfl_xor(s2n, off);
    if (p == 0) zfn[m0 + r] = s2n;
    *(uint4*)&zf_bf[(size_t)(m0 + r) * DD + (p << 3)] = make_uint4(o[0], o[1], o[2], o[3]);
  }
}

// ---- K3: fine VQ; blocks self-select rows by scanning ci_g ----------------
__global__ __launch_bounds__(256) void k3_fine(
    const unsigned short* __restrict__ zf_bf, const unsigned short* __restrict__ fcbbf,
    const float* __restrict__ fcb, const float* __restrict__ cn_all,
    const float* __restrict__ zfn, const int* __restrict__ ci_g,
    float* __restrict__ out1, float* __restrict__ fine_partial)
{
  extern __shared__ char smem[];
  unsigned short* Vb  = (unsigned short*)smem;            // [256][136]
  unsigned short* zfL = (unsigned short*)(smem + 69632);  // [32][136]
  int*   list = (int*)  (smem + 78336);                   // [2048]
  int*   ridS = (int*)  (smem + 86528);                   // [32]
  float* dmS  = (float*)(smem + 86656);                   // [4][32]
  int*   imS  = (int*)  (smem + 87168);                   // [4][32]
  int*   fiS  = (int*)  (smem + 87680);                   // [32]
  int*   wsum = (int*)  (smem + 87808);                   // [8]

  const int g = blockIdx.y, cx = blockIdx.x;   // cx in [0,4)
  const int t = threadIdx.x, lane = t & 63, wid = t >> 6;
  const int l15 = lane & 15, lhi = lane >> 4;

  // stage full group codebook FIRST (HBM latency hides under the scan below)
#pragma unroll
  for (int i = 0; i < 16; ++i) {
    int idx = t + i * 256; int row = idx >> 4, c8 = (idx & 15) * 8;
    *(uint4*)&Vb[row * 136 + c8] = *(const uint4*)&fcbbf[((size_t)g * NK1 + row) * DD + c8];
  }
  float cnr[4];
#pragma unroll
  for (int n = 0; n < 4; ++n) cnr[n] = cn_all[g * NK1 + wid * 64 + n * 16 + l15];

  // deterministic compaction of {i : ci_g[i]==g}
  const int seg = t * 32;
  int mcount = 0;
#pragma unroll 8
  for (int q = 0; q < 32; ++q) mcount += (ci_g[seg + q] == g);
  int v = mcount;
#pragma unroll
  for (int off = 1; off < 64; off <<= 1) {
    int o = __shfl_up(v, off);
    if (lane >= off) v += o;
  }
  if (lane == 63) wsum[wid] = v;
  __syncthreads();
  if (t == 0) {
    int run = 0;
#pragma unroll
    for (int w = 0; w < 4; ++w) { int c = wsum[w]; wsum[w] = run; run += c; }
    wsum[4] = run;
  }
  __syncthreads();
  const int total = wsum[4];
  const int tcap = total > 2048 ? 2048 : total;
  {
    int j = wsum[wid] + v - mcount;
    for (int q = 0; q < 32; ++q) {
      if (ci_g[seg + q] == g) { if (j < 2048) list[j] = seg + q; ++j; }
    }
  }
  __syncthreads();

  float lp = 0.f;
  for (int r0 = cx * 32; r0 < tcap; r0 += 128) {
    __syncthreads();
    if (t < 32) ridS[t] = (r0 + t < tcap) ? list[r0 + t] : -1;
    __syncthreads();
#pragma unroll
    for (int i = 0; i < 2; ++i) {
      int idx = t + i * 256; int row = idx >> 4, c8 = (idx & 15) * 8;
      int rid = ridS[row];
      uint4 vv = make_uint4(0u, 0u, 0u, 0u);
      if (rid >= 0) vv = *(const uint4*)&zf_bf[(size_t)rid * DD + c8];
      *(uint4*)&zfL[row * 136 + c8] = vv;
    }
    __syncthreads();
    f32x4 acc[2][4];
#pragma unroll
    for (int m = 0; m < 2; ++m)
#pragma unroll
      for (int n = 0; n < 4; ++n) acc[m][n] = (f32x4){0.f, 0.f, 0.f, 0.f};
#pragma unroll
    for (int ks = 0; ks < 4; ++ks) {
      const int lk = ks * 32 + lhi * 8;
      bf16x8 a0 = *(const bf16x8*)&zfL[l15 * 136 + lk];
      bf16x8 a1 = *(const bf16x8*)&zfL[(16 + l15) * 136 + lk];
#pragma unroll
      for (int n = 0; n < 4; ++n) {
        bf16x8 b = *(const bf16x8*)&Vb[(wid * 64 + n * 16 + l15) * 136 + lk];
        acc[0][n] = __builtin_amdgcn_mfma_f32_16x16x32_bf16(a0, b, acc[0][n], 0, 0, 0);
        acc[1][n] = __builtin_amdgcn_mfma_f32_16x16x32_bf16(a1, b, acc[1][n], 0, 0, 0);
      }
    }
#pragma unroll
    for (int m = 0; m < 2; ++m)
#pragma unroll
      for (int r = 0; r < 4; ++r) {
        float bd = 3.4e38f; int bi = 0;
#pragma unroll
        for (int n = 0; n < 4; ++n) {
          int code = wid * 64 + n * 16 + l15;
          float d = cnr[n] - 2.f * acc[m][n][r];
          if (d < bd || (d == bd && code < bi)) { bd = d; bi = code; }
        }
#pragma unroll
        for (int off = 1; off < 16; off <<= 1) {
          float od = __shfl_xor(bd, off); int oi = __shfl_xor(bi, off);
          if (od < bd || (od == bd && oi < bi)) { bd = od; bi = oi; }
        }
        if (l15 == 0) {
          int row = m * 16 + lhi * 4 + r;
          dmS[wid * 32 + row] = bd; imS[wid * 32 + row] = bi;
        }
      }
    __syncthreads();
    if (t < 32) {
      float bd = dmS[t]; int bi = imS[t];
#pragma unroll
      for (int w = 1; w < 4; ++w) {
        float od = dmS[w * 32 + t]; int oi = imS[w * 32 + t];
        if (od < bd || (od == bd && oi < bi)) { bd = od; bi = oi; }
      }
      fiS[t] = bi;
      int rid = ridS[t];
      if (rid >= 0) lp += bd + zfn[rid];
    }
    __syncthreads();
    {
      const int r = t >> 3, p = t & 7;
      const int rid = ridS[r];
      if (rid >= 0) {
        const int fi = fiS[r];
        const float* qr = &fcb[((size_t)g * NK1 + fi) * DD + p * 16];
        float* orow = &out1[(size_t)rid * DD + p * 16];
#pragma unroll
        for (int q = 0; q < 4; ++q) *(float4*)&orow[q * 4] = *(const float4*)&qr[q * 4];
      }
    }
  }
#pragma unroll
  for (int off = 1; off < 32; off <<= 1) lp += __shfl_xor(lp, off);
  if (t == 0) fine_partial[g * 4 + cx] = lp;
}

// ---- K4: loss reduce (one wave) -------------------------------------------
__global__ void k_final(const float* __restrict__ coarse_partial,
                        const float* __restrict__ fine_partial,
                        float* __restrict__ outL) {
  const int t = threadIdx.x;
  float s = 0.f;
#pragma unroll
  for (int i = 0; i < 4; ++i) s += coarse_partial[t + i * 64];
#pragma unroll
  for (int i = 0; i < 4; ++i) s += fine_partial[t + i * 64];
#pragma unroll
  for (int off = 1; off < 64; off <<= 1) s += __shfl_xor(s, off);
  if (t == 0) outL[0] = 1.25f * s / 1048576.0f;
}

// ---- launcher -------------------------------------------------------------
extern "C" void kernel_launch(void* const* d_in, const int* in_sizes, int n_in,
                              void* d_out, int out_size, void* d_ws, size_t ws_size,
                              hipStream_t stream) {
  const float* x     = (const float*)d_in[0];
  const float* Wc    = (const float*)d_in[1];
  const float* bc    = (const float*)d_in[2];
  const float* gc    = (const float*)d_in[3];
  const float* betac = (const float*)d_in[4];
  const float* ccb   = (const float*)d_in[5];
  const float* Wf    = (const float*)d_in[6];
  const float* bfv   = (const float*)d_in[7];
  const float* gf    = (const float*)d_in[8];
  const float* betaf = (const float*)d_in[9];
  const float* fcb   = (const float*)d_in[10];

  float* out0 = (float*)d_out;
  float* out1 = out0 + (size_t)NB * DD;
  float* outL = out0 + (size_t)2 * NB * DD;

  char* ws = (char*)d_ws;
  unsigned short* Wcomb  = (unsigned short*)(ws);
  unsigned short* Wfz    = (unsigned short*)(ws + 524288);
  unsigned short* fcbbf  = (unsigned short*)(ws + 557056);
  unsigned short* ccbbf  = (unsigned short*)(ws + 4751360);
  float*          cn_all = (float*)(ws + 4767744);
  float*          cn_c   = (float*)(ws + 4833280);
  unsigned short* zf_bf  = (unsigned short*)(ws + 4833536);
  float*          zfn    = (float*)(ws + 6930688);
  int*            ci_g   = (int*)(ws + 6963456);
  float* coarse_partial  = (float*)(ws + 6996224);
  float* fine_partial    = (float*)(ws + 6998272);

  hipFuncSetAttribute(reinterpret_cast<const void*>(kG),
                      hipFuncAttributeMaxDynamicSharedMemorySize, 110592);
  hipFuncSetAttribute(reinterpret_cast<const void*>(k3_fine),
                      hipFuncAttributeMaxDynamicSharedMemorySize, 87840);

  hipLaunchKernelGGL(k0_convert, dim3(1229), dim3(256), 0, stream,
                     Wc, Wf, fcb, ccb, Wcomb, Wfz, fcbbf, ccbbf, cn_all, cn_c);
  hipLaunchKernelGGL(kG, dim3(256), dim3(512), 110592, stream,
                     x, Wcomb, ccbbf, ccb, bc, gc, betac, cn_c,
                     bfv, gf, betaf, Wfz,
                     out0, zf_bf, zfn, ci_g, coarse_partial);
  hipLaunchKernelGGL(k3_fine, dim3(4, 64), dim3(256), 87840, stream,
                     zf_bf, fcbbf, fcb, cn_all, zfn, ci_g, out1, fine_partial);
  hipLaunchKernelGGL(k_final, dim3(1), dim3(64), 0, stream, coarse_partial, fine_partial, outL);
}